// Round 8
// baseline (502.826 us; speedup 1.0000x reference)
//
#include <hip/hip_runtime.h>
#include <math.h>

#define Bn 32
#define Sn 512
#define Hn 1024
#define Tn 8
#define Nn 16
#define Gn 4096

#define ACC4(A,W,V) A.x = fmaf(W, V.x, A.x); A.y = fmaf(W, V.y, A.y); A.z = fmaf(W, V.z, A.z); A.w = fmaf(W, V.w, A.w)

typedef float nfloat4 __attribute__((ext_vector_type(4)));

__device__ __forceinline__ float wsum(float v){
#pragma unroll
  for (int off = 32; off; off >>= 1) v += __shfl_xor(v, off);
  return v;
}

__device__ __forceinline__ float dot16(float4 a0, float4 a1, float4 a2, float4 a3,
                                       float4 v0, float4 v1, float4 v2, float4 v3){
  float d = a0.x*v0.x + a0.y*v0.y + a0.z*v0.z + a0.w*v0.w;
  d += a1.x*v1.x + a1.y*v1.y + a1.z*v1.z + a1.w*v1.w;
  d += a2.x*v2.x + a2.y*v2.y + a2.z*v2.z + a2.w*v2.w;
  d += a3.x*v3.x + a3.y*v3.y + a3.z*v3.z + a3.w*v3.w;
  return d;
}

__device__ __forceinline__ void nt_store4(float4* p, float4 v){
  nfloat4 nv;
  nv.x = v.x; nv.y = v.y; nv.z = v.z; nv.w = v.w;
  __builtin_nontemporal_store(nv, (nfloat4*)p);
}

// ---------------- utility kernels ----------------

// both weight transposes in one launch. grid (32,32,2)
__global__ __launch_bounds__(256) void transpose2(
    const float* __restrict__ Wk, const float* __restrict__ Wk2,
    float* __restrict__ WkT, float* __restrict__ Wk2T){
  __shared__ float tile[32][33];
  const float* in  = blockIdx.z ? Wk2  : Wk;
  float*       outp= blockIdx.z ? Wk2T : WkT;
  int tx = threadIdx.x & 31, ty = threadIdx.x >> 5;
  int c0 = blockIdx.x * 32, r0 = blockIdx.y * 32;
#pragma unroll
  for (int k = 0; k < 4; ++k)
    tile[ty + 8*k][tx] = in[(size_t)(r0 + ty + 8*k) * Hn + c0 + tx];
  __syncthreads();
#pragma unroll
  for (int k = 0; k < 4; ++k)
    outp[(size_t)(c0 + ty + 8*k) * Hn + r0 + tx] = tile[tx][ty + 8*k];
}

// copy nums -> un  and  pq -> xs[:,0,:]. grid (Nn+1, Bn)
__global__ __launch_bounds__(256) void prep(
    const float4* __restrict__ nums, const float4* __restrict__ pq,
    float4* __restrict__ un, float4* __restrict__ xs){
  int n = blockIdx.x, b = blockIdx.y;
  if (n < Nn) un[((size_t)b*(Nn+Tn) + n)*256 + threadIdx.x] = nums[((size_t)b*Nn + n)*256 + threadIdx.x];
  else        xs[((size_t)b*Tn)*256 + threadIdx.x] = pq[(size_t)b*256 + threadIdx.x];
}

__global__ __launch_bounds__(256) void finalize_xs(const float4* __restrict__ xs, float4* __restrict__ uh, float4* __restrict__ un){
  int t = blockIdx.x, b = blockIdx.y;
  float4 v = xs[((size_t)b*Tn + t)*256 + threadIdx.x];
  uh[(((size_t)(Sn + t))*Bn + b)*256 + threadIdx.x] = v;
  un[((size_t)b*(Nn+Tn) + Nn + t)*256 + threadIdx.x] = v;
}

// ---------------- attention (gen loop), single-pass, all-f32 ----------------
// grid (32, B), block 512 = 8 waves x 2 rows -> 16 rows/block, 1024 blocks.
// q read directly from xk (4KB/block, L2-hot) -- no LDS staging, no barrier
// before the hidden loads. Block reduce -> 32 partials per b.
// FIRST also emits uh via NON-TEMPORAL stores (uh is never re-read; keeps
// hidden L3-resident for the 6 subsequent attends).
template<int FIRST>
__global__ __launch_bounds__(512, 8) void attend7(
    const float* __restrict__ hidden, const float* __restrict__ xk,
    float* __restrict__ ctxp, float* __restrict__ mlp, float* __restrict__ uh)
{
  const int b = blockIdx.y, p = blockIdx.x;
  const int tid = threadIdx.x, lane = tid & 63, w = tid >> 6;
  __shared__ float sM[8], sL[8];
  __shared__ float sacc[8*1024];

  const float4* xp = (const float4*)(xk + (size_t)b*Hn) + lane*4;
  float4 q0 = xp[0], q1 = xp[1], q2 = xp[2], q3 = xp[3];

  const int s0 = p*16 + w*2;
  size_t r0 = ((size_t)(s0+0)*Bn + b)*Hn, r1 = ((size_t)(s0+1)*Bn + b)*Hn;
  const float4* rp0 = (const float4*)(hidden + r0) + lane*4;
  const float4* rp1 = (const float4*)(hidden + r1) + lane*4;
  float4 u0=rp0[0], u1=rp0[1], u2=rp0[2], u3=rp0[3];
  float4 v0=rp1[0], v1=rp1[1], v2=rp1[2], v3=rp1[3];
  if (FIRST){
    float4* w0p = (float4*)(uh + r0) + lane*4;
    float4* w1p = (float4*)(uh + r1) + lane*4;
    nt_store4(w0p+0, u0); nt_store4(w0p+1, u1); nt_store4(w0p+2, u2); nt_store4(w0p+3, u3);
    nt_store4(w1p+0, v0); nt_store4(w1p+1, v1); nt_store4(w1p+2, v2); nt_store4(w1p+3, v3);
  }
  float d0 = dot16(q0,q1,q2,q3, u0,u1,u2,u3);
  float d1 = dot16(q0,q1,q2,q3, v0,v1,v2,v3);
#pragma unroll
  for (int off = 32; off; off >>= 1){ d0 += __shfl_xor(d0, off); d1 += __shfl_xor(d1, off); }
  float m_run = fmaxf(d0, d1);
  float w0 = __expf(d0 - m_run), w1 = __expf(d1 - m_run);
  float l_run = w0 + w1;
  float4 a0 = make_float4(w0*u0.x + w1*v0.x, w0*u0.y + w1*v0.y, w0*u0.z + w1*v0.z, w0*u0.w + w1*v0.w);
  float4 a1 = make_float4(w0*u1.x + w1*v1.x, w0*u1.y + w1*v1.y, w0*u1.z + w1*v1.z, w0*u1.w + w1*v1.w);
  float4 a2 = make_float4(w0*u2.x + w1*v2.x, w0*u2.y + w1*v2.y, w0*u2.z + w1*v2.z, w0*u2.w + w1*v2.w);
  float4 a3 = make_float4(w0*u3.x + w1*v3.x, w0*u3.y + w1*v3.y, w0*u3.z + w1*v3.z, w0*u3.w + w1*v3.w);

  // swizzled store: slot' = slot ^ (lane&7) -> 8 consecutive lanes cover 32 banks
  {
    int sl0 = (lane*4 + 0) ^ (lane & 7);
    int sl1 = (lane*4 + 1) ^ (lane & 7);
    int sl2 = (lane*4 + 2) ^ (lane & 7);
    int sl3 = (lane*4 + 3) ^ (lane & 7);
    *(float4*)(sacc + w*1024 + sl0*4) = a0;
    *(float4*)(sacc + w*1024 + sl1*4) = a1;
    *(float4*)(sacc + w*1024 + sl2*4) = a2;
    *(float4*)(sacc + w*1024 + sl3*4) = a3;
  }
  if (lane == 0){ sM[w] = m_run; sL[w] = l_run; }
  __syncthreads();
  float M = sM[0];
#pragma unroll
  for (int i = 1; i < 8; ++i) M = fmaxf(M, sM[i]);
  float wex[8];
#pragma unroll
  for (int i = 0; i < 8; ++i) wex[i] = __expf(sM[i] - M);
#pragma unroll
  for (int h0 = 0; h0 < 1024; h0 += 512){
    int c = h0 + tid;
    int fo = (((c >> 2) ^ ((c >> 4) & 7)) << 2) + (c & 3);
    float s = 0.f;
#pragma unroll
    for (int i = 0; i < 8; ++i) s = fmaf(sacc[i*1024 + fo], wex[i], s);
    ctxp[((size_t)b*32 + p)*1024 + c] = s;
  }
  if (tid == 0){
    float L = 0.f;
#pragma unroll
    for (int i = 0; i < 8; ++i) L = fmaf(sL[i], wex[i], L);
    mlp[((size_t)b*32 + p)*2]     = M;
    mlp[((size_t)b*32 + p)*2 + 1] = L;
  }
}

// ---------------- split-K register-tiled matvec ----------------
__global__ __launch_bounds__(256) void mv1(
    const float* __restrict__ X, int xstride,
    const float* __restrict__ M, float* __restrict__ part,
    int nj, int ktiles)
{
  __shared__ float wt[64*128];
  __shared__ float xl[64*32];
  const int t  = threadIdx.x;
  const int j0 = blockIdx.x * 128;
  const int kb = blockIdx.y;
  const int r0 = blockIdx.z * 32;
  const int R  = gridDim.z * 32;
  const int tj = t & 31, tr = t >> 5;
  float acc[4][4] = {{0.f,0.f,0.f,0.f},{0.f,0.f,0.f,0.f},{0.f,0.f,0.f,0.f},{0.f,0.f,0.f,0.f}};

  for (int kt = 0; kt < ktiles; ++kt){
    const int k0 = (kb*ktiles + kt)*64;
    __syncthreads();
    {
      int j = t >> 1;
      int kqb = (t & 1) * 8;
      const float* Mrow = M + (size_t)(j0 + j)*1024 + k0;
#pragma unroll
      for (int c = 0; c < 8; ++c){
        float4 v = *(const float4*)(Mrow + (kqb + c)*4);
        int kk = (kqb + c)*4;
        wt[(kk+0)*128 + j] = v.x;
        wt[(kk+1)*128 + j] = v.y;
        wt[(kk+2)*128 + j] = v.z;
        wt[(kk+3)*128 + j] = v.w;
      }
      int r = t >> 3;
      int kq0 = t & 7;
#pragma unroll
      for (int c = 0; c < 2; ++c){
        int kk = (kq0 + c*8)*4;
        float4 v = *(const float4*)(X + (size_t)(r0 + r)*xstride + k0 + kk);
        xl[(kk+0)*32 + r] = v.x;
        xl[(kk+1)*32 + r] = v.y;
        xl[(kk+2)*32 + r] = v.z;
        xl[(kk+3)*32 + r] = v.w;
      }
    }
    __syncthreads();
#pragma unroll 4
    for (int k = 0; k < 64; ++k){
      float4 w4 = *(const float4*)(wt + k*128 + tj*4);
      float4 x4 = *(const float4*)(xl + k*32  + tr*4);
      acc[0][0] = fmaf(x4.x, w4.x, acc[0][0]);
      acc[0][1] = fmaf(x4.x, w4.y, acc[0][1]);
      acc[0][2] = fmaf(x4.x, w4.z, acc[0][2]);
      acc[0][3] = fmaf(x4.x, w4.w, acc[0][3]);
      acc[1][0] = fmaf(x4.y, w4.x, acc[1][0]);
      acc[1][1] = fmaf(x4.y, w4.y, acc[1][1]);
      acc[1][2] = fmaf(x4.y, w4.z, acc[1][2]);
      acc[1][3] = fmaf(x4.y, w4.w, acc[1][3]);
      acc[2][0] = fmaf(x4.z, w4.x, acc[2][0]);
      acc[2][1] = fmaf(x4.z, w4.y, acc[2][1]);
      acc[2][2] = fmaf(x4.z, w4.z, acc[2][2]);
      acc[2][3] = fmaf(x4.z, w4.w, acc[2][3]);
      acc[3][0] = fmaf(x4.w, w4.x, acc[3][0]);
      acc[3][1] = fmaf(x4.w, w4.y, acc[3][1]);
      acc[3][2] = fmaf(x4.w, w4.z, acc[3][2]);
      acc[3][3] = fmaf(x4.w, w4.w, acc[3][3]);
    }
  }
  const size_t base = ((size_t)kb*R + r0 + tr*4)*nj + j0 + tj*4;
#pragma unroll
  for (int i = 0; i < 4; ++i)
    *(float4*)(part + base + (size_t)i*nj) = make_float4(acc[i][0], acc[i][1], acc[i][2], acc[i][3]);
}

__global__ __launch_bounds__(256) void mv2(
    const float* __restrict__ part, int R, int njshift, int KB,
    const float* __restrict__ b1, const float* __restrict__ b2,
    float* __restrict__ out, int rpgshift, int opg)
{
  int idx = blockIdx.x*256 + threadIdx.x;
  int nj = 1 << njshift;
  int r = idx >> njshift, j = idx & (nj - 1);
  float s = 0.f;
  if (b1) s += b1[j];
  if (b2) s += b2[j];
  size_t stride = (size_t)R << njshift;
  for (int kb = 0; kb < KB; ++kb) s += part[(size_t)kb*stride + idx];
  int orow = ((r >> rpgshift) * opg) + (r & ((1 << rpgshift) - 1));
  out[((size_t)orow << njshift) + j] = s;
}

// ---------------- genstep: fused combine + Wv matvec (split-K) ----------------
// mv1 with the X-stage replaced by on-the-fly softmax-combine of 32 partials.
// Streaming (running-max) form keeps register use low. grid (8, 16), block 256.
__global__ __launch_bounds__(256) void genstep(
    const float* __restrict__ ctxp, const float* __restrict__ mlp,
    const float* __restrict__ Wv, float* __restrict__ part)
{
  __shared__ float wt[64*128];
  __shared__ float xl[64*32];
  const int t  = threadIdx.x;
  const int j0 = blockIdx.x * 128;
  const int kb = blockIdx.y;
  const int k0 = kb*64;
  const int tj = t & 31, tr = t >> 5;

  {
    int j = t >> 1;
    int kqb = (t & 1) * 8;
    const float* Mrow = Wv + (size_t)(j0 + j)*1024 + k0;
#pragma unroll
    for (int c = 0; c < 8; ++c){
      float4 v = *(const float4*)(Mrow + (kqb + c)*4);
      int kk = (kqb + c)*4;
      wt[(kk+0)*128 + j] = v.x;
      wt[(kk+1)*128 + j] = v.y;
      wt[(kk+2)*128 + j] = v.z;
      wt[(kk+3)*128 + j] = v.w;
    }
  }
  {
    int b = t >> 3, kk = (t & 7)*8;
    float mx = -1e30f;
#pragma unroll
    for (int i = 0; i < 32; ++i) mx = fmaxf(mx, mlp[((size_t)b*32 + i)*2]);
    float L = 0.f;
    float a8[8] = {0.f,0.f,0.f,0.f,0.f,0.f,0.f,0.f};
#pragma unroll 4
    for (int i = 0; i < 32; ++i){
      float m = mlp[((size_t)b*32 + i)*2];
      float l = mlp[((size_t)b*32 + i)*2 + 1];
      float we = __expf(m - mx);
      L = fmaf(l, we, L);
      const float* cp = ctxp + ((size_t)b*32 + i)*1024 + k0 + kk;
      float4 u0 = *(const float4*)cp;
      float4 u1 = *(const float4*)(cp + 4);
      a8[0] = fmaf(we, u0.x, a8[0]); a8[1] = fmaf(we, u0.y, a8[1]);
      a8[2] = fmaf(we, u0.z, a8[2]); a8[3] = fmaf(we, u0.w, a8[3]);
      a8[4] = fmaf(we, u1.x, a8[4]); a8[5] = fmaf(we, u1.y, a8[5]);
      a8[6] = fmaf(we, u1.z, a8[6]); a8[7] = fmaf(we, u1.w, a8[7]);
    }
    float inv = 1.f / L;
#pragma unroll
    for (int q = 0; q < 8; ++q) xl[(kk + q)*32 + b] = a8[q]*inv;
  }
  __syncthreads();
  float acc[4][4] = {{0.f,0.f,0.f,0.f},{0.f,0.f,0.f,0.f},{0.f,0.f,0.f,0.f},{0.f,0.f,0.f,0.f}};
#pragma unroll 4
  for (int k = 0; k < 64; ++k){
    float4 w4 = *(const float4*)(wt + k*128 + tj*4);
    float4 x4 = *(const float4*)(xl + k*32  + tr*4);
    acc[0][0] = fmaf(x4.x, w4.x, acc[0][0]);
    acc[0][1] = fmaf(x4.x, w4.y, acc[0][1]);
    acc[0][2] = fmaf(x4.x, w4.z, acc[0][2]);
    acc[0][3] = fmaf(x4.x, w4.w, acc[0][3]);
    acc[1][0] = fmaf(x4.y, w4.x, acc[1][0]);
    acc[1][1] = fmaf(x4.y, w4.y, acc[1][1]);
    acc[1][2] = fmaf(x4.y, w4.z, acc[1][2]);
    acc[1][3] = fmaf(x4.y, w4.w, acc[1][3]);
    acc[2][0] = fmaf(x4.z, w4.x, acc[2][0]);
    acc[2][1] = fmaf(x4.z, w4.y, acc[2][1]);
    acc[2][2] = fmaf(x4.z, w4.z, acc[2][2]);
    acc[2][3] = fmaf(x4.z, w4.w, acc[2][3]);
    acc[3][0] = fmaf(x4.w, w4.x, acc[3][0]);
    acc[3][1] = fmaf(x4.w, w4.y, acc[3][1]);
    acc[3][2] = fmaf(x4.w, w4.z, acc[3][2]);
    acc[3][3] = fmaf(x4.w, w4.w, acc[3][3]);
  }
  const size_t base = ((size_t)kb*32 + tr*4)*1024 + j0 + tj*4;
#pragma unroll
  for (int i = 0; i < 4; ++i)
    *(float4*)(part + base + (size_t)i*1024) = make_float4(acc[i][0], acc[i][1], acc[i][2], acc[i][3]);
}

// ---------------- stage-2 kernels ----------------

__global__ __launch_bounds__(512) void scores2_kernel(
    const float* __restrict__ hidden, const float* __restrict__ xk2, float* __restrict__ sc)
{
  int b = blockIdx.y, p = blockIdx.x;
  int lane = threadIdx.x & 63, w = threadIdx.x >> 6;
  int t0 = (w & 3) * 2, rh = w >> 2;
  const float4* qa = (const float4*)(xk2 + ((size_t)b*Tn + t0  )*Hn) + lane*4;
  const float4* qb = (const float4*)(xk2 + ((size_t)b*Tn + t0+1)*Hn) + lane*4;
  float4 a0=qa[0], a1=qa[1], a2=qa[2], a3=qa[3];
  float4 c0=qb[0], c1=qb[1], c2=qb[2], c3=qb[3];
#pragma unroll 2
  for (int r = 0; r < 8; ++r){
    int s = p*16 + rh*8 + r;
    const float4* row = (const float4*)(hidden + ((size_t)s*Bn + b)*Hn) + lane*4;
    float4 v0=row[0], v1=row[1], v2=row[2], v3=row[3];
    float d0 = wsum(dot16(a0,a1,a2,a3, v0,v1,v2,v3));
    float d1 = wsum(dot16(c0,c1,c2,c3, v0,v1,v2,v3));
    if (lane == 0){
      sc[((size_t)b*Tn + t0  )*Sn + s] = d0;
      sc[((size_t)b*Tn + t0+1)*Sn + s] = d1;
    }
  }
}

__global__ __launch_bounds__(512) void ctx2f(
    const float* __restrict__ hidden, const float* __restrict__ scraw, float* __restrict__ ctx2)
{
  int b = blockIdx.y, hc = blockIdx.x, tid = threadIdx.x;
  __shared__ float al[Tn*Sn];
  for (int i = tid; i < Tn*Sn; i += 512) al[i] = scraw[(size_t)b*Tn*Sn + i];
  __syncthreads();
  {
    int r = tid >> 6, lane = tid & 63;
    float mx = -1e30f;
#pragma unroll
    for (int k = 0; k < 8; ++k) mx = fmaxf(mx, al[r*Sn + lane + k*64]);
#pragma unroll
    for (int off = 32; off; off >>= 1) mx = fmaxf(mx, __shfl_xor(mx, off));
    float e[8], s = 0.f;
#pragma unroll
    for (int k = 0; k < 8; ++k){ e[k] = __expf(al[r*Sn + lane + k*64] - mx); s += e[k]; }
#pragma unroll
    for (int off = 32; off; off >>= 1) s += __shfl_xor(s, off);
    float inv = 1.f / s;
#pragma unroll
    for (int k = 0; k < 8; ++k) al[r*Sn + lane + k*64] = e[k] * inv;
  }
  __syncthreads();
  int hloc = tid & 127, tg = tid >> 7;
  int h = hc*128 + hloc;
  int t0 = tg*2;
  float acc0 = 0.f, acc1 = 0.f;
#pragma unroll 4
  for (int s = 0; s < Sn; ++s){
    float v = hidden[((size_t)s*Bn + b)*Hn + h];
    acc0 = fmaf(al[t0*Sn + s],     v, acc0);
    acc1 = fmaf(al[(t0+1)*Sn + s], v, acc1);
  }
  ctx2[((size_t)b*Tn + t0  )*Hn + h] = acc0;
  ctx2[((size_t)b*Tn + t0+1)*Hn + h] = acc1;
}

// ---------------- LSTM: fused partial-reduce + pointwise ----------------
__global__ __launch_bounds__(256) void lstm_fused(
    const float* __restrict__ part, const float* __restrict__ b_ih,
    const float* __restrict__ b_hh, float* __restrict__ fq)
{
  int idx = blockIdx.x*256 + threadIdx.x;   // 32768
  int b = idx >> 10, h = idx & 1023;
  const size_t stride = (size_t)32*Gn;
  float gi = b_ih[h] + b_hh[h];
  float gg = b_ih[2048+h] + b_hh[2048+h];
  float go = b_ih[3072+h] + b_hh[3072+h];
  for (int kb = 0; kb < 16; ++kb){
    const float* pp = part + (size_t)kb*stride + (size_t)b*Gn;
    gi += pp[h]; gg += pp[2048+h]; go += pp[3072+h];
  }
  float si = 1.f/(1.f + __expf(-gi));
  float so = 1.f/(1.f + __expf(-go));
  float c  = si * tanhf(gg);
  fq[((size_t)b*(Tn+1) + Tn)*Hn + h] = so * tanhf(c);
}

// ---------------- host ----------------

extern "C" void kernel_launch(void* const* d_in, const int* in_sizes, int n_in,
                              void* d_out, int out_size, void* d_ws, size_t ws_size,
                              hipStream_t stream) {
  const float* hidden = (const float*)d_in[0];
  const float* nums   = (const float*)d_in[1];
  const float* pq     = (const float*)d_in[2];
  const float* Wk     = (const float*)d_in[3];
  const float* Wv     = (const float*)d_in[5];
  const float* bv     = (const float*)d_in[6];
  const float* Wk2    = (const float*)d_in[7];
  const float* Wv2    = (const float*)d_in[9];
  const float* bv2    = (const float*)d_in[10];
  const float* W_ih   = (const float*)d_in[11];
  const float* b_ih   = (const float*)d_in[13];
  const float* b_hh   = (const float*)d_in[14];

  float* out = (float*)d_out;
  float* fq  = out;                                   // (B, T+1, H)
  float* uh  = out + (size_t)Bn*(Tn+1)*Hn;            // (S+T, B, H)
  float* un  = uh + (size_t)(Sn+Tn)*Bn*Hn;            // (B, N+T, H)

  // ws layout (floats); high-water 5,146,624 floats = 20.59 MB (< proven 21.25 MB)
  float* ws    = (float*)d_ws;
  float* xs    = ws;                 // 262144
  float* ctxp  = ws + 262144;        // 1048576 (B*32*H)
  float* mlp   = ws + 1310720;       // 2048 (B*32*2)
  float* xk    = ws + 1312768;       // 32768
  float* xk2   = ws + 1345536;       // 262144
  float* sc2   = ws + 1607680;       // 131072
  float* ctx2v = ws + 1738752;       // 262144
  float* partX = ws + 2000896;       // 524288 (16*32*1024)
  float* partK = ws + 2525184;       // 524288 (16*32*1024)
  float* WkT   = ws + 3049472;       // 1048576
  float* Wk2T  = ws + 4098048;       // 1048576
  float* partS = partX;              // stage-2 partials 4*256*1024 (spans partX+partK, both dead)
  float* partL = WkT;                // LSTM partials 16*32*4096 (spans WkT+Wk2T, both dead;
                                     // rewritten every call -> replay-safe)

  transpose2<<<dim3(32,32,2), 256, 0, stream>>>(Wk, Wk2, WkT, Wk2T);
  prep<<<dim3(Nn+1, Bn), 256, 0, stream>>>((const float4*)nums, (const float4*)pq, (float4*)un, (float4*)xs);

  // xk0 = Wk^T problem_q
  mv1<<<dim3(8,16,1), 256, 0, stream>>>(pq, Hn, WkT, partK, Hn, 1);
  mv2<<<128, 256, 0, stream>>>(partK, 32, 10, 16, nullptr, nullptr, xk, 0, 1);

  for (int t = 1; t < Tn; ++t){
    if (t == 1) attend7<1><<<dim3(32,Bn), 512, 0, stream>>>(hidden, xk, ctxp, mlp, uh);
    else        attend7<0><<<dim3(32,Bn), 512, 0, stream>>>(hidden, xk, ctxp, mlp, uh);
    genstep<<<dim3(8,16), 256, 0, stream>>>(ctxp, mlp, Wv, partX);
    mv2<<<128, 256, 0, stream>>>(partX, 32, 10, 16, bv, nullptr, xs + (size_t)t*Hn, 0, Tn);
    if (t < Tn-1){
      mv1<<<dim3(8,16,1), 256, 0, stream>>>(xs + (size_t)t*Hn, Tn*Hn, WkT, partK, Hn, 1);
      mv2<<<128, 256, 0, stream>>>(partK, 32, 10, 16, nullptr, nullptr, xk, 0, 1);
    }
  }

  // stage 2
  mv1<<<dim3(8,4,8), 256, 0, stream>>>(xs, Hn, Wk2T, partS, Hn, 4);
  mv2<<<1024, 256, 0, stream>>>(partS, 256, 10, 4, nullptr, nullptr, xk2, 0, 1);
  scores2_kernel<<<dim3(32, Bn), 512, 0, stream>>>(hidden, xk2, sc2);
  ctx2f<<<dim3(8, Bn), 512, 0, stream>>>(hidden, sc2, ctx2v);
  mv1<<<dim3(8,4,8), 256, 0, stream>>>(ctx2v, Hn, Wv2, partS, Hn, 4);
  mv2<<<1024, 256, 0, stream>>>(partS, 256, 10, 4, bv2, nullptr, fq, 3, Tn+1);

  // LSTM step 1 (partials overlay WkT/Wk2T -- dead by now)
  mv1<<<dim3(32,16,1), 256, 0, stream>>>(fq, (Tn+1)*Hn, W_ih, partL, Gn, 1);
  lstm_fused<<<128, 256, 0, stream>>>(partL, b_ih, b_hh, fq);

  finalize_xs<<<dim3(Tn, Bn), 256, 0, stream>>>((const float4*)xs, (float4*)uh, (float4*)un);
}

// Round 9
// 418.346 us; speedup vs baseline: 1.2019x; 1.2019x over previous
//
#include <hip/hip_runtime.h>
#include <math.h>

#define Bn 32
#define Sn 512
#define Hn 1024
#define Tn 8
#define Nn 16
#define Gn 4096

__device__ __forceinline__ float wsum(float v){
#pragma unroll
  for (int off = 32; off; off >>= 1) v += __shfl_xor(v, off);
  return v;
}

__device__ __forceinline__ float dot16(float4 a0, float4 a1, float4 a2, float4 a3,
                                       float4 v0, float4 v1, float4 v2, float4 v3){
  float d = a0.x*v0.x + a0.y*v0.y + a0.z*v0.z + a0.w*v0.w;
  d += a1.x*v1.x + a1.y*v1.y + a1.z*v1.z + a1.w*v1.w;
  d += a2.x*v2.x + a2.y*v2.y + a2.z*v2.z + a2.w*v2.w;
  d += a3.x*v3.x + a3.y*v3.y + a3.z*v3.z + a3.w*v3.w;
  return d;
}

// ---------------- utility kernels ----------------

// both weight transposes in one launch. grid (32,32,2)
__global__ __launch_bounds__(256) void transpose2(
    const float* __restrict__ Wk, const float* __restrict__ Wk2,
    float* __restrict__ WkT, float* __restrict__ Wk2T){
  __shared__ float tile[32][33];
  const float* in  = blockIdx.z ? Wk2  : Wk;
  float*       outp= blockIdx.z ? Wk2T : WkT;
  int tx = threadIdx.x & 31, ty = threadIdx.x >> 5;
  int c0 = blockIdx.x * 32, r0 = blockIdx.y * 32;
#pragma unroll
  for (int k = 0; k < 4; ++k)
    tile[ty + 8*k][tx] = in[(size_t)(r0 + ty + 8*k) * Hn + c0 + tx];
  __syncthreads();
#pragma unroll
  for (int k = 0; k < 4; ++k)
    outp[(size_t)(c0 + ty + 8*k) * Hn + r0 + tx] = tile[tx][ty + 8*k];
}

// copy nums -> un  and  pq -> xs[:,0,:]. grid (Nn+1, Bn)
__global__ __launch_bounds__(256) void prep(
    const float4* __restrict__ nums, const float4* __restrict__ pq,
    float4* __restrict__ un, float4* __restrict__ xs){
  int n = blockIdx.x, b = blockIdx.y;
  if (n < Nn) un[((size_t)b*(Nn+Tn) + n)*256 + threadIdx.x] = nums[((size_t)b*Nn + n)*256 + threadIdx.x];
  else        xs[((size_t)b*Tn)*256 + threadIdx.x] = pq[(size_t)b*256 + threadIdx.x];
}

__global__ __launch_bounds__(256) void finalize_xs(const float4* __restrict__ xs, float4* __restrict__ uh, float4* __restrict__ un){
  int t = blockIdx.x, b = blockIdx.y;
  float4 v = xs[((size_t)b*Tn + t)*256 + threadIdx.x];
  uh[(((size_t)(Sn + t))*Bn + b)*256 + threadIdx.x] = v;
  un[((size_t)b*(Nn+Tn) + Nn + t)*256 + threadIdx.x] = v;
}

// ---------------- attention (gen loop), single-pass, all-f32 ----------------
// grid (32, B), block 512 = 8 waves x 2 rows. COALESCED loads: lane l holds
// float4 indices {l, l+64, l+128, l+192} of each 1024-float row -- every load
// instruction is 64 lanes x 16B contiguous (1KB). Wave-sum dot is invariant
// to the lane permutation (q uses the same layout). Block reduce -> 32
// partials per b. FIRST also emits uh with cached coalesced stores.
template<int FIRST>
__global__ __launch_bounds__(512, 8) void attend8(
    const float* __restrict__ hidden, const float* __restrict__ xk,
    float* __restrict__ ctxp, float* __restrict__ mlp, float* __restrict__ uh)
{
  const int b = blockIdx.y, p = blockIdx.x;
  const int tid = threadIdx.x, lane = tid & 63, w = tid >> 6;
  __shared__ float sM[8], sL[8];
  __shared__ float sacc[8*1024];

  const float4* xp = (const float4*)(xk + (size_t)b*Hn) + lane;
  float4 q0 = xp[0], q1 = xp[64], q2 = xp[128], q3 = xp[192];

  const int s0 = p*16 + w*2;
  size_t r0 = ((size_t)(s0+0)*Bn + b)*Hn, r1 = ((size_t)(s0+1)*Bn + b)*Hn;
  const float4* rp0 = (const float4*)(hidden + r0) + lane;
  const float4* rp1 = (const float4*)(hidden + r1) + lane;
  float4 u0=rp0[0], u1=rp0[64], u2=rp0[128], u3=rp0[192];
  float4 v0=rp1[0], v1=rp1[64], v2=rp1[128], v3=rp1[192];
  if (FIRST){
    float4* w0p = (float4*)(uh + r0) + lane;
    float4* w1p = (float4*)(uh + r1) + lane;
    w0p[0]=u0; w0p[64]=u1; w0p[128]=u2; w0p[192]=u3;
    w1p[0]=v0; w1p[64]=v1; w1p[128]=v2; w1p[192]=v3;
  }
  float d0 = dot16(q0,q1,q2,q3, u0,u1,u2,u3);
  float d1 = dot16(q0,q1,q2,q3, v0,v1,v2,v3);
#pragma unroll
  for (int off = 32; off; off >>= 1){ d0 += __shfl_xor(d0, off); d1 += __shfl_xor(d1, off); }
  float m_run = fmaxf(d0, d1);
  float w0 = __expf(d0 - m_run), w1 = __expf(d1 - m_run);
  float l_run = w0 + w1;
  float4 a0 = make_float4(w0*u0.x + w1*v0.x, w0*u0.y + w1*v0.y, w0*u0.z + w1*v0.z, w0*u0.w + w1*v0.w);
  float4 a1 = make_float4(w0*u1.x + w1*v1.x, w0*u1.y + w1*v1.y, w0*u1.z + w1*v1.z, w0*u1.w + w1*v1.w);
  float4 a2 = make_float4(w0*u2.x + w1*v2.x, w0*u2.y + w1*v2.y, w0*u2.z + w1*v2.z, w0*u2.w + w1*v2.w);
  float4 a3 = make_float4(w0*u3.x + w1*v3.x, w0*u3.y + w1*v3.y, w0*u3.z + w1*v3.z, w0*u3.w + w1*v3.w);

  // LDS store: slot sl_k = (lane*4+k)^(lane&7) -- proven conflict-free (R8: 0 conflicts).
  // a_k holds ctx floats [k*256 + 4*lane, +4).
  {
    int sl0 = (lane*4 + 0) ^ (lane & 7);
    int sl1 = (lane*4 + 1) ^ (lane & 7);
    int sl2 = (lane*4 + 2) ^ (lane & 7);
    int sl3 = (lane*4 + 3) ^ (lane & 7);
    *(float4*)(sacc + w*1024 + sl0*4) = a0;
    *(float4*)(sacc + w*1024 + sl1*4) = a1;
    *(float4*)(sacc + w*1024 + sl2*4) = a2;
    *(float4*)(sacc + w*1024 + sl3*4) = a3;
  }
  if (lane == 0){ sM[w] = m_run; sL[w] = l_run; }
  __syncthreads();
  float M = sM[0];
#pragma unroll
  for (int i = 1; i < 8; ++i) M = fmaxf(M, sM[i]);
  float wex[8];
#pragma unroll
  for (int i = 0; i < 8; ++i) wex[i] = __expf(sM[i] - M);
  // output float c lives at slot ((4*l + k)^(l&7)) with k=c>>8, l=(c>>2)&63, j=c&3
#pragma unroll
  for (int h0 = 0; h0 < 1024; h0 += 512){
    int c = h0 + tid;
    int k = c >> 8, l = (c >> 2) & 63, j = c & 3;
    int fo = ((((l << 2) + k) ^ (l & 7)) << 2) + j;
    float s = 0.f;
#pragma unroll
    for (int i = 0; i < 8; ++i) s = fmaf(sacc[i*1024 + fo], wex[i], s);
    ctxp[((size_t)b*32 + p)*1024 + c] = s;
  }
  if (tid == 0){
    float L = 0.f;
#pragma unroll
    for (int i = 0; i < 8; ++i) L = fmaf(sL[i], wex[i], L);
    mlp[((size_t)b*32 + p)*2]     = M;
    mlp[((size_t)b*32 + p)*2 + 1] = L;
  }
}

// ---------------- split-K register-tiled matvec ----------------
__global__ __launch_bounds__(256) void mv1(
    const float* __restrict__ X, int xstride,
    const float* __restrict__ M, float* __restrict__ part,
    int nj, int ktiles)
{
  __shared__ float wt[64*128];
  __shared__ float xl[64*32];
  const int t  = threadIdx.x;
  const int j0 = blockIdx.x * 128;
  const int kb = blockIdx.y;
  const int r0 = blockIdx.z * 32;
  const int R  = gridDim.z * 32;
  const int tj = t & 31, tr = t >> 5;
  float acc[4][4] = {{0.f,0.f,0.f,0.f},{0.f,0.f,0.f,0.f},{0.f,0.f,0.f,0.f},{0.f,0.f,0.f,0.f}};

  for (int kt = 0; kt < ktiles; ++kt){
    const int k0 = (kb*ktiles + kt)*64;
    __syncthreads();
    {
      int j = t >> 1;
      int kqb = (t & 1) * 8;
      const float* Mrow = M + (size_t)(j0 + j)*1024 + k0;
#pragma unroll
      for (int c = 0; c < 8; ++c){
        float4 v = *(const float4*)(Mrow + (kqb + c)*4);
        int kk = (kqb + c)*4;
        wt[(kk+0)*128 + j] = v.x;
        wt[(kk+1)*128 + j] = v.y;
        wt[(kk+2)*128 + j] = v.z;
        wt[(kk+3)*128 + j] = v.w;
      }
      int r = t >> 3;
      int kq0 = t & 7;
#pragma unroll
      for (int c = 0; c < 2; ++c){
        int kk = (kq0 + c*8)*4;
        float4 v = *(const float4*)(X + (size_t)(r0 + r)*xstride + k0 + kk);
        xl[(kk+0)*32 + r] = v.x;
        xl[(kk+1)*32 + r] = v.y;
        xl[(kk+2)*32 + r] = v.z;
        xl[(kk+3)*32 + r] = v.w;
      }
    }
    __syncthreads();
#pragma unroll 4
    for (int k = 0; k < 64; ++k){
      float4 w4 = *(const float4*)(wt + k*128 + tj*4);
      float4 x4 = *(const float4*)(xl + k*32  + tr*4);
      acc[0][0] = fmaf(x4.x, w4.x, acc[0][0]);
      acc[0][1] = fmaf(x4.x, w4.y, acc[0][1]);
      acc[0][2] = fmaf(x4.x, w4.z, acc[0][2]);
      acc[0][3] = fmaf(x4.x, w4.w, acc[0][3]);
      acc[1][0] = fmaf(x4.y, w4.x, acc[1][0]);
      acc[1][1] = fmaf(x4.y, w4.y, acc[1][1]);
      acc[1][2] = fmaf(x4.y, w4.z, acc[1][2]);
      acc[1][3] = fmaf(x4.y, w4.w, acc[1][3]);
      acc[2][0] = fmaf(x4.z, w4.x, acc[2][0]);
      acc[2][1] = fmaf(x4.z, w4.y, acc[2][1]);
      acc[2][2] = fmaf(x4.z, w4.z, acc[2][2]);
      acc[2][3] = fmaf(x4.z, w4.w, acc[2][3]);
      acc[3][0] = fmaf(x4.w, w4.x, acc[3][0]);
      acc[3][1] = fmaf(x4.w, w4.y, acc[3][1]);
      acc[3][2] = fmaf(x4.w, w4.z, acc[3][2]);
      acc[3][3] = fmaf(x4.w, w4.w, acc[3][3]);
    }
  }
  const size_t base = ((size_t)kb*R + r0 + tr*4)*nj + j0 + tj*4;
#pragma unroll
  for (int i = 0; i < 4; ++i)
    *(float4*)(part + base + (size_t)i*nj) = make_float4(acc[i][0], acc[i][1], acc[i][2], acc[i][3]);
}

__global__ __launch_bounds__(256) void mv2(
    const float* __restrict__ part, int R, int njshift, int KB,
    const float* __restrict__ b1, const float* __restrict__ b2,
    float* __restrict__ out, int rpgshift, int opg)
{
  int idx = blockIdx.x*256 + threadIdx.x;
  int nj = 1 << njshift;
  int r = idx >> njshift, j = idx & (nj - 1);
  float s = 0.f;
  if (b1) s += b1[j];
  if (b2) s += b2[j];
  size_t stride = (size_t)R << njshift;
  for (int kb = 0; kb < KB; ++kb) s += part[(size_t)kb*stride + idx];
  int orow = ((r >> rpgshift) * opg) + (r & ((1 << rpgshift) - 1));
  out[((size_t)orow << njshift) + j] = s;
}

// ---------------- genstep: fused combine + Wv matvec (split-K) ----------------
__global__ __launch_bounds__(256) void genstep(
    const float* __restrict__ ctxp, const float* __restrict__ mlp,
    const float* __restrict__ Wv, float* __restrict__ part)
{
  __shared__ float wt[64*128];
  __shared__ float xl[64*32];
  const int t  = threadIdx.x;
  const int j0 = blockIdx.x * 128;
  const int kb = blockIdx.y;
  const int k0 = kb*64;
  const int tj = t & 31, tr = t >> 5;

  {
    int j = t >> 1;
    int kqb = (t & 1) * 8;
    const float* Mrow = Wv + (size_t)(j0 + j)*1024 + k0;
#pragma unroll
    for (int c = 0; c < 8; ++c){
      float4 v = *(const float4*)(Mrow + (kqb + c)*4);
      int kk = (kqb + c)*4;
      wt[(kk+0)*128 + j] = v.x;
      wt[(kk+1)*128 + j] = v.y;
      wt[(kk+2)*128 + j] = v.z;
      wt[(kk+3)*128 + j] = v.w;
    }
  }
  {
    int b = t >> 3, kk = (t & 7)*8;
    float mx = -1e30f;
#pragma unroll
    for (int i = 0; i < 32; ++i) mx = fmaxf(mx, mlp[((size_t)b*32 + i)*2]);
    float L = 0.f;
    float a8[8] = {0.f,0.f,0.f,0.f,0.f,0.f,0.f,0.f};
#pragma unroll 4
    for (int i = 0; i < 32; ++i){
      float m = mlp[((size_t)b*32 + i)*2];
      float l = mlp[((size_t)b*32 + i)*2 + 1];
      float we = __expf(m - mx);
      L = fmaf(l, we, L);
      const float* cp = ctxp + ((size_t)b*32 + i)*1024 + k0 + kk;
      float4 u0 = *(const float4*)cp;
      float4 u1 = *(const float4*)(cp + 4);
      a8[0] = fmaf(we, u0.x, a8[0]); a8[1] = fmaf(we, u0.y, a8[1]);
      a8[2] = fmaf(we, u0.z, a8[2]); a8[3] = fmaf(we, u0.w, a8[3]);
      a8[4] = fmaf(we, u1.x, a8[4]); a8[5] = fmaf(we, u1.y, a8[5]);
      a8[6] = fmaf(we, u1.z, a8[6]); a8[7] = fmaf(we, u1.w, a8[7]);
    }
    float inv = 1.f / L;
#pragma unroll
    for (int q = 0; q < 8; ++q) xl[(kk + q)*32 + b] = a8[q]*inv;
  }
  __syncthreads();
  float acc[4][4] = {{0.f,0.f,0.f,0.f},{0.f,0.f,0.f,0.f},{0.f,0.f,0.f,0.f},{0.f,0.f,0.f,0.f}};
#pragma unroll 4
  for (int k = 0; k < 64; ++k){
    float4 w4 = *(const float4*)(wt + k*128 + tj*4);
    float4 x4 = *(const float4*)(xl + k*32  + tr*4);
    acc[0][0] = fmaf(x4.x, w4.x, acc[0][0]);
    acc[0][1] = fmaf(x4.x, w4.y, acc[0][1]);
    acc[0][2] = fmaf(x4.x, w4.z, acc[0][2]);
    acc[0][3] = fmaf(x4.x, w4.w, acc[0][3]);
    acc[1][0] = fmaf(x4.y, w4.x, acc[1][0]);
    acc[1][1] = fmaf(x4.y, w4.y, acc[1][1]);
    acc[1][2] = fmaf(x4.y, w4.z, acc[1][2]);
    acc[1][3] = fmaf(x4.y, w4.w, acc[1][3]);
    acc[2][0] = fmaf(x4.z, w4.x, acc[2][0]);
    acc[2][1] = fmaf(x4.z, w4.y, acc[2][1]);
    acc[2][2] = fmaf(x4.z, w4.z, acc[2][2]);
    acc[2][3] = fmaf(x4.z, w4.w, acc[2][3]);
    acc[3][0] = fmaf(x4.w, w4.x, acc[3][0]);
    acc[3][1] = fmaf(x4.w, w4.y, acc[3][1]);
    acc[3][2] = fmaf(x4.w, w4.z, acc[3][2]);
    acc[3][3] = fmaf(x4.w, w4.w, acc[3][3]);
  }
  const size_t base = ((size_t)kb*32 + tr*4)*1024 + j0 + tj*4;
#pragma unroll
  for (int i = 0; i < 4; ++i)
    *(float4*)(part + base + (size_t)i*1024) = make_float4(acc[i][0], acc[i][1], acc[i][2], acc[i][3]);
}

// ---------------- stage-2 kernels ----------------

// coalesced variant: lane l holds float4 indices {l, l+64, l+128, l+192};
// q uses the same layout so the wave-sum dot is unchanged.
__global__ __launch_bounds__(512) void scores2_kernel(
    const float* __restrict__ hidden, const float* __restrict__ xk2, float* __restrict__ sc)
{
  int b = blockIdx.y, p = blockIdx.x;
  int lane = threadIdx.x & 63, w = threadIdx.x >> 6;
  int t0 = (w & 3) * 2, rh = w >> 2;
  const float4* qa = (const float4*)(xk2 + ((size_t)b*Tn + t0  )*Hn) + lane;
  const float4* qb = (const float4*)(xk2 + ((size_t)b*Tn + t0+1)*Hn) + lane;
  float4 a0=qa[0], a1=qa[64], a2=qa[128], a3=qa[192];
  float4 c0=qb[0], c1=qb[64], c2=qb[128], c3=qb[192];
#pragma unroll 2
  for (int r = 0; r < 8; ++r){
    int s = p*16 + rh*8 + r;
    const float4* row = (const float4*)(hidden + ((size_t)s*Bn + b)*Hn) + lane;
    float4 v0=row[0], v1=row[64], v2=row[128], v3=row[192];
    float d0 = wsum(dot16(a0,a1,a2,a3, v0,v1,v2,v3));
    float d1 = wsum(dot16(c0,c1,c2,c3, v0,v1,v2,v3));
    if (lane == 0){
      sc[((size_t)b*Tn + t0  )*Sn + s] = d0;
      sc[((size_t)b*Tn + t0+1)*Sn + s] = d1;
    }
  }
}

__global__ __launch_bounds__(512) void ctx2f(
    const float* __restrict__ hidden, const float* __restrict__ scraw, float* __restrict__ ctx2)
{
  int b = blockIdx.y, hc = blockIdx.x, tid = threadIdx.x;
  __shared__ float al[Tn*Sn];
  for (int i = tid; i < Tn*Sn; i += 512) al[i] = scraw[(size_t)b*Tn*Sn + i];
  __syncthreads();
  {
    int r = tid >> 6, lane = tid & 63;
    float mx = -1e30f;
#pragma unroll
    for (int k = 0; k < 8; ++k) mx = fmaxf(mx, al[r*Sn + lane + k*64]);
#pragma unroll
    for (int off = 32; off; off >>= 1) mx = fmaxf(mx, __shfl_xor(mx, off));
    float e[8], s = 0.f;
#pragma unroll
    for (int k = 0; k < 8; ++k){ e[k] = __expf(al[r*Sn + lane + k*64] - mx); s += e[k]; }
#pragma unroll
    for (int off = 32; off; off >>= 1) s += __shfl_xor(s, off);
    float inv = 1.f / s;
#pragma unroll
    for (int k = 0; k < 8; ++k) al[r*Sn + lane + k*64] = e[k] * inv;
  }
  __syncthreads();
  int hloc = tid & 127, tg = tid >> 7;
  int h = hc*128 + hloc;
  int t0 = tg*2;
  float acc0 = 0.f, acc1 = 0.f;
#pragma unroll 4
  for (int s = 0; s < Sn; ++s){
    float v = hidden[((size_t)s*Bn + b)*Hn + h];
    acc0 = fmaf(al[t0*Sn + s],     v, acc0);
    acc1 = fmaf(al[(t0+1)*Sn + s], v, acc1);
  }
  ctx2[((size_t)b*Tn + t0  )*Hn + h] = acc0;
  ctx2[((size_t)b*Tn + t0+1)*Hn + h] = acc1;
}

// ---------------- LSTM: fused partial-reduce + pointwise ----------------
__global__ __launch_bounds__(256) void lstm_fused(
    const float* __restrict__ part, const float* __restrict__ b_ih,
    const float* __restrict__ b_hh, float* __restrict__ fq)
{
  int idx = blockIdx.x*256 + threadIdx.x;   // 32768
  int b = idx >> 10, h = idx & 1023;
  const size_t stride = (size_t)32*Gn;
  float gi = b_ih[h] + b_hh[h];
  float gg = b_ih[2048+h] + b_hh[2048+h];
  float go = b_ih[3072+h] + b_hh[3072+h];
  for (int kb = 0; kb < 16; ++kb){
    const float* pp = part + (size_t)kb*stride + (size_t)b*Gn;
    gi += pp[h]; gg += pp[2048+h]; go += pp[3072+h];
  }
  float si = 1.f/(1.f + __expf(-gi));
  float so = 1.f/(1.f + __expf(-go));
  float c  = si * tanhf(gg);
  fq[((size_t)b*(Tn+1) + Tn)*Hn + h] = so * tanhf(c);
}

// ---------------- host ----------------

extern "C" void kernel_launch(void* const* d_in, const int* in_sizes, int n_in,
                              void* d_out, int out_size, void* d_ws, size_t ws_size,
                              hipStream_t stream) {
  const float* hidden = (const float*)d_in[0];
  const float* nums   = (const float*)d_in[1];
  const float* pq     = (const float*)d_in[2];
  const float* Wk     = (const float*)d_in[3];
  const float* Wv     = (const float*)d_in[5];
  const float* bv     = (const float*)d_in[6];
  const float* Wk2    = (const float*)d_in[7];
  const float* Wv2    = (const float*)d_in[9];
  const float* bv2    = (const float*)d_in[10];
  const float* W_ih   = (const float*)d_in[11];
  const float* b_ih   = (const float*)d_in[13];
  const float* b_hh   = (const float*)d_in[14];

  float* out = (float*)d_out;
  float* fq  = out;                                   // (B, T+1, H)
  float* uh  = out + (size_t)Bn*(Tn+1)*Hn;            // (S+T, B, H)
  float* un  = uh + (size_t)(Sn+Tn)*Bn*Hn;            // (B, N+T, H)

  // ws layout (floats); high-water 5,146,624 floats = 20.59 MB (< proven 21.25 MB)
  float* ws    = (float*)d_ws;
  float* xs    = ws;                 // 262144
  float* ctxp  = ws + 262144;        // 1048576 (B*32*H)
  float* mlp   = ws + 1310720;       // 2048 (B*32*2)
  float* xk    = ws + 1312768;       // 32768
  float* xk2   = ws + 1345536;       // 262144
  float* sc2   = ws + 1607680;       // 131072
  float* ctx2v = ws + 1738752;       // 262144
  float* partX = ws + 2000896;       // 524288 (16*32*1024)
  float* partK = ws + 2525184;       // 524288 (16*32*1024)
  float* WkT   = ws + 3049472;       // 1048576
  float* Wk2T  = ws + 4098048;       // 1048576
  float* partS = partX;              // stage-2 partials 4*256*1024 (spans partX+partK, both dead)
  float* partL = WkT;                // LSTM partials 16*32*4096 (spans WkT+Wk2T, both dead;
                                     // rewritten every call -> replay-safe)

  transpose2<<<dim3(32,32,2), 256, 0, stream>>>(Wk, Wk2, WkT, Wk2T);
  prep<<<dim3(Nn+1, Bn), 256, 0, stream>>>((const float4*)nums, (const float4*)pq, (float4*)un, (float4*)xs);

  // xk0 = Wk^T problem_q
  mv1<<<dim3(8,16,1), 256, 0, stream>>>(pq, Hn, WkT, partK, Hn, 1);
  mv2<<<128, 256, 0, stream>>>(partK, 32, 10, 16, nullptr, nullptr, xk, 0, 1);

  for (int t = 1; t < Tn; ++t){
    if (t == 1) attend8<1><<<dim3(32,Bn), 512, 0, stream>>>(hidden, xk, ctxp, mlp, uh);
    else        attend8<0><<<dim3(32,Bn), 512, 0, stream>>>(hidden, xk, ctxp, mlp, uh);
    genstep<<<dim3(8,16), 256, 0, stream>>>(ctxp, mlp, Wv, partX);
    mv2<<<128, 256, 0, stream>>>(partX, 32, 10, 16, bv, nullptr, xs + (size_t)t*Hn, 0, Tn);
    if (t < Tn-1){
      mv1<<<dim3(8,16,1), 256, 0, stream>>>(xs + (size_t)t*Hn, Tn*Hn, WkT, partK, Hn, 1);
      mv2<<<128, 256, 0, stream>>>(partK, 32, 10, 16, nullptr, nullptr, xk, 0, 1);
    }
  }

  // stage 2
  mv1<<<dim3(8,4,8), 256, 0, stream>>>(xs, Hn, Wk2T, partS, Hn, 4);
  mv2<<<1024, 256, 0, stream>>>(partS, 256, 10, 4, nullptr, nullptr, xk2, 0, 1);
  scores2_kernel<<<dim3(32, Bn), 512, 0, stream>>>(hidden, xk2, sc2);
  ctx2f<<<dim3(8, Bn), 512, 0, stream>>>(hidden, sc2, ctx2v);
  mv1<<<dim3(8,4,8), 256, 0, stream>>>(ctx2v, Hn, Wv2, partS, Hn, 4);
  mv2<<<1024, 256, 0, stream>>>(partS, 256, 10, 4, bv2, nullptr, fq, 3, Tn+1);

  // LSTM step 1 (partials overlay WkT/Wk2T -- dead by now)
  mv1<<<dim3(32,16,1), 256, 0, stream>>>(fq, (Tn+1)*Hn, W_ih, partL, Gn, 1);
  lstm_fused<<<128, 256, 0, stream>>>(partL, b_ih, b_hh, fq);

  finalize_xs<<<dim3(Tn, Bn), 256, 0, stream>>>((const float4*)xs, (float4*)uh, (float4*)un);
}

// Round 10
// 379.723 us; speedup vs baseline: 1.3242x; 1.1017x over previous
//
#include <hip/hip_runtime.h>
#include <math.h>

#define Bn 32
#define Sn 512
#define Hn 1024
#define Tn 8
#define Nn 16
#define Gn 4096

__device__ __forceinline__ float wsum(float v){
#pragma unroll
  for (int off = 32; off; off >>= 1) v += __shfl_xor(v, off);
  return v;
}

__device__ __forceinline__ float dot16(float4 a0, float4 a1, float4 a2, float4 a3,
                                       float4 v0, float4 v1, float4 v2, float4 v3){
  float d = a0.x*v0.x + a0.y*v0.y + a0.z*v0.z + a0.w*v0.w;
  d += a1.x*v1.x + a1.y*v1.y + a1.z*v1.z + a1.w*v1.w;
  d += a2.x*v2.x + a2.y*v2.y + a2.z*v2.z + a2.w*v2.w;
  d += a3.x*v3.x + a3.y*v3.y + a3.z*v3.z + a3.w*v3.w;
  return d;
}

// ---------------- utility kernels ----------------

__global__ __launch_bounds__(256) void transpose2(
    const float* __restrict__ Wk, const float* __restrict__ Wk2,
    float* __restrict__ WkT, float* __restrict__ Wk2T){
  __shared__ float tile[32][33];
  const float* in  = blockIdx.z ? Wk2  : Wk;
  float*       outp= blockIdx.z ? Wk2T : WkT;
  int tx = threadIdx.x & 31, ty = threadIdx.x >> 5;
  int c0 = blockIdx.x * 32, r0 = blockIdx.y * 32;
#pragma unroll
  for (int k = 0; k < 4; ++k)
    tile[ty + 8*k][tx] = in[(size_t)(r0 + ty + 8*k) * Hn + c0 + tx];
  __syncthreads();
#pragma unroll
  for (int k = 0; k < 4; ++k)
    outp[(size_t)(c0 + ty + 8*k) * Hn + r0 + tx] = tile[tx][ty + 8*k];
}

__global__ __launch_bounds__(256) void prep(
    const float4* __restrict__ nums, const float4* __restrict__ pq,
    float4* __restrict__ un, float4* __restrict__ xs){
  int n = blockIdx.x, b = blockIdx.y;
  if (n < Nn) un[((size_t)b*(Nn+Tn) + n)*256 + threadIdx.x] = nums[((size_t)b*Nn + n)*256 + threadIdx.x];
  else        xs[((size_t)b*Tn)*256 + threadIdx.x] = pq[(size_t)b*256 + threadIdx.x];
}

__global__ __launch_bounds__(256) void finalize_xs(const float4* __restrict__ xs, float4* __restrict__ uh, float4* __restrict__ un){
  int t = blockIdx.x, b = blockIdx.y;
  float4 v = xs[((size_t)b*Tn + t)*256 + threadIdx.x];
  uh[(((size_t)(Sn + t))*Bn + b)*256 + threadIdx.x] = v;
  un[((size_t)b*(Nn+Tn) + Nn + t)*256 + threadIdx.x] = v;
}

// ---------------- attention (gen loop): 4 rows/wave, batched loads ----------
// grid (16, B), block 512 = 8 waves x 4 rows -> 32 rows/block, 512 blocks
// (2 blocks/CU). 16 coalesced loads issued up-front per wave (4x the MLP of
// the 2-row version). Weights computed AFTER block max -> block reduce is a
// plain sum. 16 partials per b. FIRST also emits uh (folds the 64MB copy).
template<int FIRST>
__global__ __launch_bounds__(512, 4) void attend9(
    const float* __restrict__ hidden, const float* __restrict__ xk,
    float* __restrict__ ctxp, float* __restrict__ mlp, float* __restrict__ uh)
{
  const int b = blockIdx.y, p = blockIdx.x;
  const int tid = threadIdx.x, lane = tid & 63, w = tid >> 6;
  __shared__ float sM[8], sL[8];
  __shared__ float sacc[8*1024];

  const float4* xp = (const float4*)(xk + (size_t)b*Hn) + lane;
  float4 q0 = xp[0], q1 = xp[64], q2 = xp[128], q3 = xp[192];

  const int s0 = p*32 + w*4;
  size_t ro[4];
#pragma unroll
  for (int i = 0; i < 4; ++i) ro[i] = ((size_t)(s0+i)*Bn + b)*Hn;
  float4 u[4][4];
#pragma unroll
  for (int i = 0; i < 4; ++i){
    const float4* rp = (const float4*)(hidden + ro[i]) + lane;
    u[i][0]=rp[0]; u[i][1]=rp[64]; u[i][2]=rp[128]; u[i][3]=rp[192];
  }
  if (FIRST){
#pragma unroll
    for (int i = 0; i < 4; ++i){
      float4* wp = (float4*)(uh + ro[i]) + lane;
      wp[0]=u[i][0]; wp[64]=u[i][1]; wp[128]=u[i][2]; wp[192]=u[i][3];
    }
  }
  float d[4];
#pragma unroll
  for (int i = 0; i < 4; ++i) d[i] = dot16(q0,q1,q2,q3, u[i][0],u[i][1],u[i][2],u[i][3]);
#pragma unroll
  for (int off = 32; off; off >>= 1){
#pragma unroll
    for (int i = 0; i < 4; ++i) d[i] += __shfl_xor(d[i], off);
  }
  float mw = fmaxf(fmaxf(d[0], d[1]), fmaxf(d[2], d[3]));
  sM[w] = mw;
  __syncthreads();
  float M = sM[0];
#pragma unroll
  for (int i = 1; i < 8; ++i) M = fmaxf(M, sM[i]);
  float wi[4], lw = 0.f;
#pragma unroll
  for (int i = 0; i < 4; ++i){ wi[i] = __expf(d[i] - M); lw += wi[i]; }
  float4 a0, a1, a2, a3;
  a0 = make_float4(wi[0]*u[0][0].x, wi[0]*u[0][0].y, wi[0]*u[0][0].z, wi[0]*u[0][0].w);
  a1 = make_float4(wi[0]*u[0][1].x, wi[0]*u[0][1].y, wi[0]*u[0][1].z, wi[0]*u[0][1].w);
  a2 = make_float4(wi[0]*u[0][2].x, wi[0]*u[0][2].y, wi[0]*u[0][2].z, wi[0]*u[0][2].w);
  a3 = make_float4(wi[0]*u[0][3].x, wi[0]*u[0][3].y, wi[0]*u[0][3].z, wi[0]*u[0][3].w);
#pragma unroll
  for (int i = 1; i < 4; ++i){
    a0.x = fmaf(wi[i], u[i][0].x, a0.x); a0.y = fmaf(wi[i], u[i][0].y, a0.y);
    a0.z = fmaf(wi[i], u[i][0].z, a0.z); a0.w = fmaf(wi[i], u[i][0].w, a0.w);
    a1.x = fmaf(wi[i], u[i][1].x, a1.x); a1.y = fmaf(wi[i], u[i][1].y, a1.y);
    a1.z = fmaf(wi[i], u[i][1].z, a1.z); a1.w = fmaf(wi[i], u[i][1].w, a1.w);
    a2.x = fmaf(wi[i], u[i][2].x, a2.x); a2.y = fmaf(wi[i], u[i][2].y, a2.y);
    a2.z = fmaf(wi[i], u[i][2].z, a2.z); a2.w = fmaf(wi[i], u[i][2].w, a2.w);
    a3.x = fmaf(wi[i], u[i][3].x, a3.x); a3.y = fmaf(wi[i], u[i][3].y, a3.y);
    a3.z = fmaf(wi[i], u[i][3].z, a3.z); a3.w = fmaf(wi[i], u[i][3].w, a3.w);
  }

  // LDS store: slot sl_k = (lane*4+k)^(lane&7) -- proven conflict-free (R8/R9).
  {
    int sl0 = (lane*4 + 0) ^ (lane & 7);
    int sl1 = (lane*4 + 1) ^ (lane & 7);
    int sl2 = (lane*4 + 2) ^ (lane & 7);
    int sl3 = (lane*4 + 3) ^ (lane & 7);
    *(float4*)(sacc + w*1024 + sl0*4) = a0;
    *(float4*)(sacc + w*1024 + sl1*4) = a1;
    *(float4*)(sacc + w*1024 + sl2*4) = a2;
    *(float4*)(sacc + w*1024 + sl3*4) = a3;
  }
  if (lane == 0) sL[w] = lw;
  __syncthreads();
  // all waves share block max M -> plain sums
#pragma unroll
  for (int h0 = 0; h0 < 1024; h0 += 512){
    int c = h0 + tid;
    int k = c >> 8, l = (c >> 2) & 63, j = c & 3;
    int fo = ((((l << 2) + k) ^ (l & 7)) << 2) + j;
    float s = 0.f;
#pragma unroll
    for (int i = 0; i < 8; ++i) s += sacc[i*1024 + fo];
    ctxp[((size_t)b*16 + p)*1024 + c] = s;
  }
  if (tid == 0){
    float L = 0.f;
#pragma unroll
    for (int i = 0; i < 8; ++i) L += sL[i];
    mlp[((size_t)b*16 + p)*2]     = M;
    mlp[((size_t)b*16 + p)*2 + 1] = L;
  }
}

// ---------------- split-K register-tiled matvec ----------------
__global__ __launch_bounds__(256) void mv1(
    const float* __restrict__ X, int xstride,
    const float* __restrict__ M, float* __restrict__ part,
    int nj, int ktiles)
{
  __shared__ float wt[64*128];
  __shared__ float xl[64*32];
  const int t  = threadIdx.x;
  const int j0 = blockIdx.x * 128;
  const int kb = blockIdx.y;
  const int r0 = blockIdx.z * 32;
  const int R  = gridDim.z * 32;
  const int tj = t & 31, tr = t >> 5;
  float acc[4][4] = {{0.f,0.f,0.f,0.f},{0.f,0.f,0.f,0.f},{0.f,0.f,0.f,0.f},{0.f,0.f,0.f,0.f}};

  for (int kt = 0; kt < ktiles; ++kt){
    const int k0 = (kb*ktiles + kt)*64;
    __syncthreads();
    {
      int j = t >> 1;
      int kqb = (t & 1) * 8;
      const float* Mrow = M + (size_t)(j0 + j)*1024 + k0;
#pragma unroll
      for (int c = 0; c < 8; ++c){
        float4 v = *(const float4*)(Mrow + (kqb + c)*4);
        int kk = (kqb + c)*4;
        wt[(kk+0)*128 + j] = v.x;
        wt[(kk+1)*128 + j] = v.y;
        wt[(kk+2)*128 + j] = v.z;
        wt[(kk+3)*128 + j] = v.w;
      }
      int r = t >> 3;
      int kq0 = t & 7;
#pragma unroll
      for (int c = 0; c < 2; ++c){
        int kk = (kq0 + c*8)*4;
        float4 v = *(const float4*)(X + (size_t)(r0 + r)*xstride + k0 + kk);
        xl[(kk+0)*32 + r] = v.x;
        xl[(kk+1)*32 + r] = v.y;
        xl[(kk+2)*32 + r] = v.z;
        xl[(kk+3)*32 + r] = v.w;
      }
    }
    __syncthreads();
#pragma unroll 4
    for (int k = 0; k < 64; ++k){
      float4 w4 = *(const float4*)(wt + k*128 + tj*4);
      float4 x4 = *(const float4*)(xl + k*32  + tr*4);
      acc[0][0] = fmaf(x4.x, w4.x, acc[0][0]);
      acc[0][1] = fmaf(x4.x, w4.y, acc[0][1]);
      acc[0][2] = fmaf(x4.x, w4.z, acc[0][2]);
      acc[0][3] = fmaf(x4.x, w4.w, acc[0][3]);
      acc[1][0] = fmaf(x4.y, w4.x, acc[1][0]);
      acc[1][1] = fmaf(x4.y, w4.y, acc[1][1]);
      acc[1][2] = fmaf(x4.y, w4.z, acc[1][2]);
      acc[1][3] = fmaf(x4.y, w4.w, acc[1][3]);
      acc[2][0] = fmaf(x4.z, w4.x, acc[2][0]);
      acc[2][1] = fmaf(x4.z, w4.y, acc[2][1]);
      acc[2][2] = fmaf(x4.z, w4.z, acc[2][2]);
      acc[2][3] = fmaf(x4.z, w4.w, acc[2][3]);
      acc[3][0] = fmaf(x4.w, w4.x, acc[3][0]);
      acc[3][1] = fmaf(x4.w, w4.y, acc[3][1]);
      acc[3][2] = fmaf(x4.w, w4.z, acc[3][2]);
      acc[3][3] = fmaf(x4.w, w4.w, acc[3][3]);
    }
  }
  const size_t base = ((size_t)kb*R + r0 + tr*4)*nj + j0 + tj*4;
#pragma unroll
  for (int i = 0; i < 4; ++i)
    *(float4*)(part + base + (size_t)i*nj) = make_float4(acc[i][0], acc[i][1], acc[i][2], acc[i][3]);
}

__global__ __launch_bounds__(256) void mv2(
    const float* __restrict__ part, int R, int njshift, int KB,
    const float* __restrict__ b1, const float* __restrict__ b2,
    float* __restrict__ out, int rpgshift, int opg)
{
  int idx = blockIdx.x*256 + threadIdx.x;
  int nj = 1 << njshift;
  int r = idx >> njshift, j = idx & (nj - 1);
  float s = 0.f;
  if (b1) s += b1[j];
  if (b2) s += b2[j];
  size_t stride = (size_t)R << njshift;
  for (int kb = 0; kb < KB; ++kb) s += part[(size_t)kb*stride + idx];
  int orow = ((r >> rpgshift) * opg) + (r & ((1 << rpgshift) - 1));
  out[((size_t)orow << njshift) + j] = s;
}

// ---------------- genstep: fused combine + Wv matvec (split-K) ----------------
// combine of 16 partials fused into the X-stage. grid (8, 16), block 256.
__global__ __launch_bounds__(256) void genstep(
    const float* __restrict__ ctxp, const float* __restrict__ mlp,
    const float* __restrict__ Wv, float* __restrict__ part)
{
  __shared__ float wt[64*128];
  __shared__ float xl[64*32];
  const int t  = threadIdx.x;
  const int j0 = blockIdx.x * 128;
  const int kb = blockIdx.y;
  const int k0 = kb*64;
  const int tj = t & 31, tr = t >> 5;

  {
    int j = t >> 1;
    int kqb = (t & 1) * 8;
    const float* Mrow = Wv + (size_t)(j0 + j)*1024 + k0;
#pragma unroll
    for (int c = 0; c < 8; ++c){
      float4 v = *(const float4*)(Mrow + (kqb + c)*4);
      int kk = (kqb + c)*4;
      wt[(kk+0)*128 + j] = v.x;
      wt[(kk+1)*128 + j] = v.y;
      wt[(kk+2)*128 + j] = v.z;
      wt[(kk+3)*128 + j] = v.w;
    }
  }
  {
    int b = t >> 3, kk = (t & 7)*8;
    float mx = -1e30f;
#pragma unroll
    for (int i = 0; i < 16; ++i) mx = fmaxf(mx, mlp[((size_t)b*16 + i)*2]);
    float L = 0.f;
    float a8[8] = {0.f,0.f,0.f,0.f,0.f,0.f,0.f,0.f};
#pragma unroll 4
    for (int i = 0; i < 16; ++i){
      float m = mlp[((size_t)b*16 + i)*2];
      float l = mlp[((size_t)b*16 + i)*2 + 1];
      float we = __expf(m - mx);
      L = fmaf(l, we, L);
      const float* cp = ctxp + ((size_t)b*16 + i)*1024 + k0 + kk;
      float4 u0 = *(const float4*)cp;
      float4 u1 = *(const float4*)(cp + 4);
      a8[0] = fmaf(we, u0.x, a8[0]); a8[1] = fmaf(we, u0.y, a8[1]);
      a8[2] = fmaf(we, u0.z, a8[2]); a8[3] = fmaf(we, u0.w, a8[3]);
      a8[4] = fmaf(we, u1.x, a8[4]); a8[5] = fmaf(we, u1.y, a8[5]);
      a8[6] = fmaf(we, u1.z, a8[6]); a8[7] = fmaf(we, u1.w, a8[7]);
    }
    float inv = 1.f / L;
#pragma unroll
    for (int q = 0; q < 8; ++q) xl[(kk + q)*32 + b] = a8[q]*inv;
  }
  __syncthreads();
  float acc[4][4] = {{0.f,0.f,0.f,0.f},{0.f,0.f,0.f,0.f},{0.f,0.f,0.f,0.f},{0.f,0.f,0.f,0.f}};
#pragma unroll 4
  for (int k = 0; k < 64; ++k){
    float4 w4 = *(const float4*)(wt + k*128 + tj*4);
    float4 x4 = *(const float4*)(xl + k*32  + tr*4);
    acc[0][0] = fmaf(x4.x, w4.x, acc[0][0]);
    acc[0][1] = fmaf(x4.x, w4.y, acc[0][1]);
    acc[0][2] = fmaf(x4.x, w4.z, acc[0][2]);
    acc[0][3] = fmaf(x4.x, w4.w, acc[0][3]);
    acc[1][0] = fmaf(x4.y, w4.x, acc[1][0]);
    acc[1][1] = fmaf(x4.y, w4.y, acc[1][1]);
    acc[1][2] = fmaf(x4.y, w4.z, acc[1][2]);
    acc[1][3] = fmaf(x4.y, w4.w, acc[1][3]);
    acc[2][0] = fmaf(x4.z, w4.x, acc[2][0]);
    acc[2][1] = fmaf(x4.z, w4.y, acc[2][1]);
    acc[2][2] = fmaf(x4.z, w4.z, acc[2][2]);
    acc[2][3] = fmaf(x4.z, w4.w, acc[2][3]);
    acc[3][0] = fmaf(x4.w, w4.x, acc[3][0]);
    acc[3][1] = fmaf(x4.w, w4.y, acc[3][1]);
    acc[3][2] = fmaf(x4.w, w4.z, acc[3][2]);
    acc[3][3] = fmaf(x4.w, w4.w, acc[3][3]);
  }
  const size_t base = ((size_t)kb*32 + tr*4)*1024 + j0 + tj*4;
#pragma unroll
  for (int i = 0; i < 4; ++i)
    *(float4*)(part + base + (size_t)i*1024) = make_float4(acc[i][0], acc[i][1], acc[i][2], acc[i][3]);
}

// ---------------- stage-2 kernels ----------------

__global__ __launch_bounds__(512) void scores2_kernel(
    const float* __restrict__ hidden, const float* __restrict__ xk2, float* __restrict__ sc)
{
  int b = blockIdx.y, p = blockIdx.x;
  int lane = threadIdx.x & 63, w = threadIdx.x >> 6;
  int t0 = (w & 3) * 2, rh = w >> 2;
  const float4* qa = (const float4*)(xk2 + ((size_t)b*Tn + t0  )*Hn) + lane;
  const float4* qb = (const float4*)(xk2 + ((size_t)b*Tn + t0+1)*Hn) + lane;
  float4 a0=qa[0], a1=qa[64], a2=qa[128], a3=qa[192];
  float4 c0=qb[0], c1=qb[64], c2=qb[128], c3=qb[192];
#pragma unroll 2
  for (int r = 0; r < 8; ++r){
    int s = p*16 + rh*8 + r;
    const float4* row = (const float4*)(hidden + ((size_t)s*Bn + b)*Hn) + lane;
    float4 v0=row[0], v1=row[64], v2=row[128], v3=row[192];
    float d0 = wsum(dot16(a0,a1,a2,a3, v0,v1,v2,v3));
    float d1 = wsum(dot16(c0,c1,c2,c3, v0,v1,v2,v3));
    if (lane == 0){
      sc[((size_t)b*Tn + t0  )*Sn + s] = d0;
      sc[((size_t)b*Tn + t0+1)*Sn + s] = d1;
    }
  }
}

// in-place softmax over 512 elems. grid (B*T), block 512.
__global__ __launch_bounds__(512) void softmax512(float* __restrict__ sc){
  int row = blockIdx.x, tid = threadIdx.x, lane = tid & 63, w = tid >> 6;
  float v = sc[(size_t)row*Sn + tid];
  float mx = v;
#pragma unroll
  for (int off = 32; off; off >>= 1) mx = fmaxf(mx, __shfl_xor(mx, off));
  __shared__ float sm[8], ss[8];
  if (lane == 0) sm[w] = mx;
  __syncthreads();
  mx = sm[0];
#pragma unroll
  for (int i = 1; i < 8; ++i) mx = fmaxf(mx, sm[i]);
  float e = __expf(v - mx);
  float s = e;
#pragma unroll
  for (int off = 32; off; off >>= 1) s += __shfl_xor(s, off);
  if (lane == 0) ss[w] = s;
  __syncthreads();
  float tot = 0.f;
#pragma unroll
  for (int i = 0; i < 8; ++i) tot += ss[i];
  sc[(size_t)row*Sn + tid] = e / tot;
}

// split-s ctx2 partials. grid (8 hc, 4 sc, 32 b) = 1024 blocks, block 512.
__global__ __launch_bounds__(512) void ctx2p(
    const float* __restrict__ hidden, const float* __restrict__ attn, float* __restrict__ part)
{
  int hc = blockIdx.x, sc = blockIdx.y, b = blockIdx.z;
  int tid = threadIdx.x, hloc = tid & 127, tg = tid >> 7;
  __shared__ float al[Tn*128];
  for (int idx = tid; idx < Tn*128; idx += 512){
    int t = idx >> 7, si = idx & 127;
    al[idx] = attn[((size_t)b*Tn + t)*Sn + sc*128 + si];
  }
  __syncthreads();
  int h = hc*128 + hloc, t0 = tg*2;
  float acc0 = 0.f, acc1 = 0.f;
#pragma unroll 4
  for (int si = 0; si < 128; ++si){
    int s = sc*128 + si;
    float v = hidden[((size_t)s*Bn + b)*Hn + h];
    acc0 = fmaf(al[t0*128 + si],     v, acc0);
    acc1 = fmaf(al[(t0+1)*128 + si], v, acc1);
  }
  part[(((size_t)sc*Bn + b)*Tn + t0  )*Hn + h] = acc0;
  part[(((size_t)sc*Bn + b)*Tn + t0+1)*Hn + h] = acc1;
}

// reduce 4 s-chunks. grid 1024, block 256.
__global__ __launch_bounds__(256) void ctx2r(const float* __restrict__ part, float* __restrict__ out){
  int idx = blockIdx.x*256 + threadIdx.x;   // 262144
  out[idx] = part[idx] + part[262144 + idx] + part[524288 + idx] + part[786432 + idx];
}

// ---------------- LSTM: fused partial-reduce + pointwise ----------------
__global__ __launch_bounds__(256) void lstm_fused(
    const float* __restrict__ part, const float* __restrict__ b_ih,
    const float* __restrict__ b_hh, float* __restrict__ fq)
{
  int idx = blockIdx.x*256 + threadIdx.x;   // 32768
  int b = idx >> 10, h = idx & 1023;
  const size_t stride = (size_t)32*Gn;
  float gi = b_ih[h] + b_hh[h];
  float gg = b_ih[2048+h] + b_hh[2048+h];
  float go = b_ih[3072+h] + b_hh[3072+h];
  for (int kb = 0; kb < 16; ++kb){
    const float* pp = part + (size_t)kb*stride + (size_t)b*Gn;
    gi += pp[h]; gg += pp[2048+h]; go += pp[3072+h];
  }
  float si = 1.f/(1.f + __expf(-gi));
  float so = 1.f/(1.f + __expf(-go));
  float c  = si * tanhf(gg);
  fq[((size_t)b*(Tn+1) + Tn)*Hn + h] = so * tanhf(c);
}

// ---------------- host ----------------

extern "C" void kernel_launch(void* const* d_in, const int* in_sizes, int n_in,
                              void* d_out, int out_size, void* d_ws, size_t ws_size,
                              hipStream_t stream) {
  const float* hidden = (const float*)d_in[0];
  const float* nums   = (const float*)d_in[1];
  const float* pq     = (const float*)d_in[2];
  const float* Wk     = (const float*)d_in[3];
  const float* Wv     = (const float*)d_in[5];
  const float* bv     = (const float*)d_in[6];
  const float* Wk2    = (const float*)d_in[7];
  const float* Wv2    = (const float*)d_in[9];
  const float* bv2    = (const float*)d_in[10];
  const float* W_ih   = (const float*)d_in[11];
  const float* b_ih   = (const float*)d_in[13];
  const float* b_hh   = (const float*)d_in[14];

  float* out = (float*)d_out;
  float* fq  = out;                                   // (B, T+1, H)
  float* uh  = out + (size_t)Bn*(Tn+1)*Hn;            // (S+T, B, H)
  float* un  = uh + (size_t)(Sn+Tn)*Bn*Hn;            // (B, N+T, H)

  // ws layout (floats); high-water 5,146,624 floats = 20.59 MB (< proven 21.25 MB)
  float* ws    = (float*)d_ws;
  float* xs    = ws;                 // 262144
  float* ctxp  = ws + 262144;        // region 1048576 (B*16*H = 524288 used)
  float* mlp   = ws + 1310720;       // 2048 (B*16*2 = 512 used)
  float* xk    = ws + 1312768;       // 32768
  float* xk2   = ws + 1345536;       // 262144
  float* sc2   = ws + 1607680;       // 131072
  float* ctx2v = ws + 1738752;       // 262144
  float* partX = ws + 2000896;       // 524288 (16*32*1024)
  float* partK = ws + 2525184;       // 524288 (16*32*1024)
  float* WkT   = ws + 3049472;       // 1048576
  float* Wk2T  = ws + 4098048;       // 1048576
  float* partS = partX;              // stage-2 partials 4*256*1024 (spans partX+partK, both dead)
  float* c2part= partX;              // ctx2 split-s partials 4*256*1024 (same region, disjoint lifetime)
  float* partL = WkT;                // LSTM partials 16*32*4096 (spans WkT+Wk2T, both dead;
                                     // rewritten every call -> replay-safe)

  transpose2<<<dim3(32,32,2), 256, 0, stream>>>(Wk, Wk2, WkT, Wk2T);
  prep<<<dim3(Nn+1, Bn), 256, 0, stream>>>((const float4*)nums, (const float4*)pq, (float4*)un, (float4*)xs);

  // xk0 = Wk^T problem_q
  mv1<<<dim3(8,16,1), 256, 0, stream>>>(pq, Hn, WkT, partK, Hn, 1);
  mv2<<<128, 256, 0, stream>>>(partK, 32, 10, 16, nullptr, nullptr, xk, 0, 1);

  for (int t = 1; t < Tn; ++t){
    if (t == 1) attend9<1><<<dim3(16,Bn), 512, 0, stream>>>(hidden, xk, ctxp, mlp, uh);
    else        attend9<0><<<dim3(16,Bn), 512, 0, stream>>>(hidden, xk, ctxp, mlp, uh);
    genstep<<<dim3(8,16), 256, 0, stream>>>(ctxp, mlp, Wv, partX);
    mv2<<<128, 256, 0, stream>>>(partX, 32, 10, 16, bv, nullptr, xs + (size_t)t*Hn, 0, Tn);
    if (t < Tn-1){
      mv1<<<dim3(8,16,1), 256, 0, stream>>>(xs + (size_t)t*Hn, Tn*Hn, WkT, partK, Hn, 1);
      mv2<<<128, 256, 0, stream>>>(partK, 32, 10, 16, nullptr, nullptr, xk, 0, 1);
    }
  }

  // stage 2
  mv1<<<dim3(8,4,8), 256, 0, stream>>>(xs, Hn, Wk2T, partS, Hn, 4);
  mv2<<<1024, 256, 0, stream>>>(partS, 256, 10, 4, nullptr, nullptr, xk2, 0, 1);
  scores2_kernel<<<dim3(32, Bn), 512, 0, stream>>>(hidden, xk2, sc2);
  softmax512<<<Bn*Tn, 512, 0, stream>>>(sc2);
  ctx2p<<<dim3(8, 4, Bn), 512, 0, stream>>>(hidden, sc2, c2part);
  ctx2r<<<1024, 256, 0, stream>>>(c2part, ctx2v);
  mv1<<<dim3(8,4,8), 256, 0, stream>>>(ctx2v, Hn, Wv2, partS, Hn, 4);
  mv2<<<1024, 256, 0, stream>>>(partS, 256, 10, 4, bv2, nullptr, fq, 3, Tn+1);

  // LSTM step 1 (partials overlay WkT/Wk2T -- dead by now)
  mv1<<<dim3(32,16,1), 256, 0, stream>>>(fq, (Tn+1)*Hn, W_ih, partL, Gn, 1);
  lstm_fused<<<128, 256, 0, stream>>>(partL, b_ih, b_hh, fq);

  finalize_xs<<<dim3(Tn, Bn), 256, 0, stream>>>((const float4*)xs, (float4*)uh, (float4*)un);
}

// Round 11
// 379.709 us; speedup vs baseline: 1.3242x; 1.0000x over previous
//
#include <hip/hip_runtime.h>
#include <math.h>

#define Bn 32
#define Sn 512
#define Hn 1024
#define Tn 8
#define Nn 16
#define Gn 4096

__device__ __forceinline__ float wsum(float v){
#pragma unroll
  for (int off = 32; off; off >>= 1) v += __shfl_xor(v, off);
  return v;
}

__device__ __forceinline__ float dot16(float4 a0, float4 a1, float4 a2, float4 a3,
                                       float4 v0, float4 v1, float4 v2, float4 v3){
  float d = a0.x*v0.x + a0.y*v0.y + a0.z*v0.z + a0.w*v0.w;
  d += a1.x*v1.x + a1.y*v1.y + a1.z*v1.z + a1.w*v1.w;
  d += a2.x*v2.x + a2.y*v2.y + a2.z*v2.z + a2.w*v2.w;
  d += a3.x*v3.x + a3.y*v3.y + a3.z*v3.z + a3.w*v3.w;
  return d;
}

// ---------------- utility kernels ----------------

// three weight transposes in one launch. grid (32,32,3)
__global__ __launch_bounds__(256) void transpose3(
    const float* __restrict__ Wk, const float* __restrict__ Wk2, const float* __restrict__ Wv,
    float* __restrict__ WkT, float* __restrict__ Wk2T, float* __restrict__ WvT){
  __shared__ float tile[32][33];
  const float* in  = (blockIdx.z == 0) ? Wk  : (blockIdx.z == 1) ? Wk2  : Wv;
  float*       outp= (blockIdx.z == 0) ? WkT : (blockIdx.z == 1) ? Wk2T : WvT;
  int tx = threadIdx.x & 31, ty = threadIdx.x >> 5;
  int c0 = blockIdx.x * 32, r0 = blockIdx.y * 32;
#pragma unroll
  for (int k = 0; k < 4; ++k)
    tile[ty + 8*k][tx] = in[(size_t)(r0 + ty + 8*k) * Hn + c0 + tx];
  __syncthreads();
#pragma unroll
  for (int k = 0; k < 4; ++k)
    outp[(size_t)(c0 + ty + 8*k) * Hn + r0 + tx] = tile[tx][ty + 8*k];
}

__global__ __launch_bounds__(256) void prep(
    const float4* __restrict__ nums, const float4* __restrict__ pq,
    float4* __restrict__ un, float4* __restrict__ xs){
  int n = blockIdx.x, b = blockIdx.y;
  if (n < Nn) un[((size_t)b*(Nn+Tn) + n)*256 + threadIdx.x] = nums[((size_t)b*Nn + n)*256 + threadIdx.x];
  else        xs[((size_t)b*Tn)*256 + threadIdx.x] = pq[(size_t)b*256 + threadIdx.x];
}

__global__ __launch_bounds__(256) void finalize_xs(const float4* __restrict__ xs, float4* __restrict__ uh, float4* __restrict__ un){
  int t = blockIdx.x, b = blockIdx.y;
  float4 v = xs[((size_t)b*Tn + t)*256 + threadIdx.x];
  uh[(((size_t)(Sn + t))*Bn + b)*256 + threadIdx.x] = v;
  un[((size_t)b*(Nn+Tn) + Nn + t)*256 + threadIdx.x] = v;
}

// dk[j] = dot(bv, WkT[j]) over 1024. grid 256, block 256 (4 waves, 1 j each).
__global__ __launch_bounds__(256) void dkv(
    const float* __restrict__ bv, const float* __restrict__ WkT, float* __restrict__ dk)
{
  int lane = threadIdx.x & 63, w = threadIdx.x >> 6;
  int j = blockIdx.x*4 + w;
  const float4* rp = (const float4*)(WkT + (size_t)j*Hn) + lane;
  const float4* bp = (const float4*)bv + lane;
  float4 v0=rp[0], v1=rp[64], v2=rp[128], v3=rp[192];
  float4 b0=bp[0], b1=bp[64], b2=bp[128], b3=bp[192];
  float d = wsum(dot16(b0,b1,b2,b3, v0,v1,v2,v3));
  if (lane == 0) dk[j] = d;
}

// ---------------- attention (gen loop): 4 rows/wave, batched coalesced loads
template<int FIRST>
__global__ __launch_bounds__(512, 4) void attend9(
    const float* __restrict__ hidden, const float* __restrict__ xk,
    float* __restrict__ ctxp, float* __restrict__ mlp, float* __restrict__ uh)
{
  const int b = blockIdx.y, p = blockIdx.x;
  const int tid = threadIdx.x, lane = tid & 63, w = tid >> 6;
  __shared__ float sM[8], sL[8];
  __shared__ float sacc[8*1024];

  const float4* xp = (const float4*)(xk + (size_t)b*Hn) + lane;
  float4 q0 = xp[0], q1 = xp[64], q2 = xp[128], q3 = xp[192];

  const int s0 = p*32 + w*4;
  size_t ro[4];
#pragma unroll
  for (int i = 0; i < 4; ++i) ro[i] = ((size_t)(s0+i)*Bn + b)*Hn;
  float4 u[4][4];
#pragma unroll
  for (int i = 0; i < 4; ++i){
    const float4* rp = (const float4*)(hidden + ro[i]) + lane;
    u[i][0]=rp[0]; u[i][1]=rp[64]; u[i][2]=rp[128]; u[i][3]=rp[192];
  }
  if (FIRST){
#pragma unroll
    for (int i = 0; i < 4; ++i){
      float4* wp = (float4*)(uh + ro[i]) + lane;
      wp[0]=u[i][0]; wp[64]=u[i][1]; wp[128]=u[i][2]; wp[192]=u[i][3];
    }
  }
  float d[4];
#pragma unroll
  for (int i = 0; i < 4; ++i) d[i] = dot16(q0,q1,q2,q3, u[i][0],u[i][1],u[i][2],u[i][3]);
#pragma unroll
  for (int off = 32; off; off >>= 1){
#pragma unroll
    for (int i = 0; i < 4; ++i) d[i] += __shfl_xor(d[i], off);
  }
  float mw = fmaxf(fmaxf(d[0], d[1]), fmaxf(d[2], d[3]));
  sM[w] = mw;
  __syncthreads();
  float M = sM[0];
#pragma unroll
  for (int i = 1; i < 8; ++i) M = fmaxf(M, sM[i]);
  float wi[4], lw = 0.f;
#pragma unroll
  for (int i = 0; i < 4; ++i){ wi[i] = __expf(d[i] - M); lw += wi[i]; }
  float4 a0, a1, a2, a3;
  a0 = make_float4(wi[0]*u[0][0].x, wi[0]*u[0][0].y, wi[0]*u[0][0].z, wi[0]*u[0][0].w);
  a1 = make_float4(wi[0]*u[0][1].x, wi[0]*u[0][1].y, wi[0]*u[0][1].z, wi[0]*u[0][1].w);
  a2 = make_float4(wi[0]*u[0][2].x, wi[0]*u[0][2].y, wi[0]*u[0][2].z, wi[0]*u[0][2].w);
  a3 = make_float4(wi[0]*u[0][3].x, wi[0]*u[0][3].y, wi[0]*u[0][3].z, wi[0]*u[0][3].w);
#pragma unroll
  for (int i = 1; i < 4; ++i){
    a0.x = fmaf(wi[i], u[i][0].x, a0.x); a0.y = fmaf(wi[i], u[i][0].y, a0.y);
    a0.z = fmaf(wi[i], u[i][0].z, a0.z); a0.w = fmaf(wi[i], u[i][0].w, a0.w);
    a1.x = fmaf(wi[i], u[i][1].x, a1.x); a1.y = fmaf(wi[i], u[i][1].y, a1.y);
    a1.z = fmaf(wi[i], u[i][1].z, a1.z); a1.w = fmaf(wi[i], u[i][1].w, a1.w);
    a2.x = fmaf(wi[i], u[i][2].x, a2.x); a2.y = fmaf(wi[i], u[i][2].y, a2.y);
    a2.z = fmaf(wi[i], u[i][2].z, a2.z); a2.w = fmaf(wi[i], u[i][2].w, a2.w);
    a3.x = fmaf(wi[i], u[i][3].x, a3.x); a3.y = fmaf(wi[i], u[i][3].y, a3.y);
    a3.z = fmaf(wi[i], u[i][3].z, a3.z); a3.w = fmaf(wi[i], u[i][3].w, a3.w);
  }
  {
    int sl0 = (lane*4 + 0) ^ (lane & 7);
    int sl1 = (lane*4 + 1) ^ (lane & 7);
    int sl2 = (lane*4 + 2) ^ (lane & 7);
    int sl3 = (lane*4 + 3) ^ (lane & 7);
    *(float4*)(sacc + w*1024 + sl0*4) = a0;
    *(float4*)(sacc + w*1024 + sl1*4) = a1;
    *(float4*)(sacc + w*1024 + sl2*4) = a2;
    *(float4*)(sacc + w*1024 + sl3*4) = a3;
  }
  if (lane == 0) sL[w] = lw;
  __syncthreads();
#pragma unroll
  for (int h0 = 0; h0 < 1024; h0 += 512){
    int c = h0 + tid;
    int k = c >> 8, l = (c >> 2) & 63, j = c & 3;
    int fo = ((((l << 2) + k) ^ (l & 7)) << 2) + j;
    float s = 0.f;
#pragma unroll
    for (int i = 0; i < 8; ++i) s += sacc[i*1024 + fo];
    ctxp[((size_t)b*16 + p)*1024 + c] = s;
  }
  if (tid == 0){
    float L = 0.f;
#pragma unroll
    for (int i = 0; i < 8; ++i) L += sL[i];
    mlp[((size_t)b*16 + p)*2]     = M;
    mlp[((size_t)b*16 + p)*2 + 1] = L;
  }
}

// ---------------- split-K register-tiled matvec ----------------
__global__ __launch_bounds__(256) void mv1(
    const float* __restrict__ X, int xstride,
    const float* __restrict__ M, float* __restrict__ part,
    int nj, int ktiles)
{
  __shared__ float wt[64*128];
  __shared__ float xl[64*32];
  const int t  = threadIdx.x;
  const int j0 = blockIdx.x * 128;
  const int kb = blockIdx.y;
  const int r0 = blockIdx.z * 32;
  const int R  = gridDim.z * 32;
  const int tj = t & 31, tr = t >> 5;
  float acc[4][4] = {{0.f,0.f,0.f,0.f},{0.f,0.f,0.f,0.f},{0.f,0.f,0.f,0.f},{0.f,0.f,0.f,0.f}};

  for (int kt = 0; kt < ktiles; ++kt){
    const int k0 = (kb*ktiles + kt)*64;
    __syncthreads();
    {
      int j = t >> 1;
      int kqb = (t & 1) * 8;
      const float* Mrow = M + (size_t)(j0 + j)*1024 + k0;
#pragma unroll
      for (int c = 0; c < 8; ++c){
        float4 v = *(const float4*)(Mrow + (kqb + c)*4);
        int kk = (kqb + c)*4;
        wt[(kk+0)*128 + j] = v.x;
        wt[(kk+1)*128 + j] = v.y;
        wt[(kk+2)*128 + j] = v.z;
        wt[(kk+3)*128 + j] = v.w;
      }
      int r = t >> 3;
      int kq0 = t & 7;
#pragma unroll
      for (int c = 0; c < 2; ++c){
        int kk = (kq0 + c*8)*4;
        float4 v = *(const float4*)(X + (size_t)(r0 + r)*xstride + k0 + kk);
        xl[(kk+0)*32 + r] = v.x;
        xl[(kk+1)*32 + r] = v.y;
        xl[(kk+2)*32 + r] = v.z;
        xl[(kk+3)*32 + r] = v.w;
      }
    }
    __syncthreads();
#pragma unroll 4
    for (int k = 0; k < 64; ++k){
      float4 w4 = *(const float4*)(wt + k*128 + tj*4);
      float4 x4 = *(const float4*)(xl + k*32  + tr*4);
      acc[0][0] = fmaf(x4.x, w4.x, acc[0][0]);
      acc[0][1] = fmaf(x4.x, w4.y, acc[0][1]);
      acc[0][2] = fmaf(x4.x, w4.z, acc[0][2]);
      acc[0][3] = fmaf(x4.x, w4.w, acc[0][3]);
      acc[1][0] = fmaf(x4.y, w4.x, acc[1][0]);
      acc[1][1] = fmaf(x4.y, w4.y, acc[1][1]);
      acc[1][2] = fmaf(x4.y, w4.z, acc[1][2]);
      acc[1][3] = fmaf(x4.y, w4.w, acc[1][3]);
      acc[2][0] = fmaf(x4.z, w4.x, acc[2][0]);
      acc[2][1] = fmaf(x4.z, w4.y, acc[2][1]);
      acc[2][2] = fmaf(x4.z, w4.z, acc[2][2]);
      acc[2][3] = fmaf(x4.z, w4.w, acc[2][3]);
      acc[3][0] = fmaf(x4.w, w4.x, acc[3][0]);
      acc[3][1] = fmaf(x4.w, w4.y, acc[3][1]);
      acc[3][2] = fmaf(x4.w, w4.z, acc[3][2]);
      acc[3][3] = fmaf(x4.w, w4.w, acc[3][3]);
    }
  }
  const size_t base = ((size_t)kb*R + r0 + tr*4)*nj + j0 + tj*4;
#pragma unroll
  for (int i = 0; i < 4; ++i)
    *(float4*)(part + base + (size_t)i*nj) = make_float4(acc[i][0], acc[i][1], acc[i][2], acc[i][3]);
}

__global__ __launch_bounds__(256) void mv2(
    const float* __restrict__ part, int R, int njshift, int KB,
    const float* __restrict__ b1, const float* __restrict__ b2,
    float* __restrict__ out, int rpgshift, int opg)
{
  int idx = blockIdx.x*256 + threadIdx.x;
  int nj = 1 << njshift;
  int r = idx >> njshift, j = idx & (nj - 1);
  float s = 0.f;
  if (b1) s += b1[j];
  if (b2) s += b2[j];
  size_t stride = (size_t)R << njshift;
  for (int kb = 0; kb < KB; ++kb) s += part[(size_t)kb*stride + idx];
  int orow = ((r >> rpgshift) * opg) + (r & ((1 << rpgshift) - 1));
  out[((size_t)orow << njshift) + j] = s;
}

// ---------------- genw: fused combine + D matvec; side-writes normalized ctx
// FULL=1: grid (8,16); FULL=0 (combine-only, t=Tn-1): grid (1,16).
template<int FULL>
__global__ __launch_bounds__(256) void genw(
    const float* __restrict__ ctxp, const float* __restrict__ mlp,
    const float* __restrict__ D, float* __restrict__ part, float* __restrict__ ctxout)
{
  __shared__ float wt[64*128];
  __shared__ float xl[64*32];
  const int t  = threadIdx.x;
  const int j0 = blockIdx.x * 128;
  const int kb = blockIdx.y;
  const int k0 = kb*64;
  const int tj = t & 31, tr = t >> 5;

  if (FULL){
    int j = t >> 1;
    int kqb = (t & 1) * 8;
    const float* Mrow = D + (size_t)(j0 + j)*1024 + k0;
#pragma unroll
    for (int c = 0; c < 8; ++c){
      float4 v = *(const float4*)(Mrow + (kqb + c)*4);
      int kk = (kqb + c)*4;
      wt[(kk+0)*128 + j] = v.x;
      wt[(kk+1)*128 + j] = v.y;
      wt[(kk+2)*128 + j] = v.z;
      wt[(kk+3)*128 + j] = v.w;
    }
  }
  {
    int b = t >> 3, kk = (t & 7)*8;
    float mx = -1e30f;
#pragma unroll
    for (int i = 0; i < 16; ++i) mx = fmaxf(mx, mlp[((size_t)b*16 + i)*2]);
    float L = 0.f;
    float a8[8] = {0.f,0.f,0.f,0.f,0.f,0.f,0.f,0.f};
#pragma unroll 4
    for (int i = 0; i < 16; ++i){
      float m = mlp[((size_t)b*16 + i)*2];
      float l = mlp[((size_t)b*16 + i)*2 + 1];
      float we = __expf(m - mx);
      L = fmaf(l, we, L);
      const float* cp = ctxp + ((size_t)b*16 + i)*1024 + k0 + kk;
      float4 u0 = *(const float4*)cp;
      float4 u1 = *(const float4*)(cp + 4);
      a8[0] = fmaf(we, u0.x, a8[0]); a8[1] = fmaf(we, u0.y, a8[1]);
      a8[2] = fmaf(we, u0.z, a8[2]); a8[3] = fmaf(we, u0.w, a8[3]);
      a8[4] = fmaf(we, u1.x, a8[4]); a8[5] = fmaf(we, u1.y, a8[5]);
      a8[6] = fmaf(we, u1.z, a8[6]); a8[7] = fmaf(we, u1.w, a8[7]);
    }
    float inv = 1.f / L;
#pragma unroll
    for (int q = 0; q < 8; ++q){
      float c = a8[q]*inv;
      if (FULL) xl[(kk + q)*32 + b] = c;
      if (!FULL || blockIdx.x == 0) ctxout[(size_t)b*1024 + k0 + kk + q] = c;
    }
  }
  if (!FULL) return;
  __syncthreads();
  float acc[4][4] = {{0.f,0.f,0.f,0.f},{0.f,0.f,0.f,0.f},{0.f,0.f,0.f,0.f},{0.f,0.f,0.f,0.f}};
#pragma unroll 4
  for (int k = 0; k < 64; ++k){
    float4 w4 = *(const float4*)(wt + k*128 + tj*4);
    float4 x4 = *(const float4*)(xl + k*32  + tr*4);
    acc[0][0] = fmaf(x4.x, w4.x, acc[0][0]);
    acc[0][1] = fmaf(x4.x, w4.y, acc[0][1]);
    acc[0][2] = fmaf(x4.x, w4.z, acc[0][2]);
    acc[0][3] = fmaf(x4.x, w4.w, acc[0][3]);
    acc[1][0] = fmaf(x4.y, w4.x, acc[1][0]);
    acc[1][1] = fmaf(x4.y, w4.y, acc[1][1]);
    acc[1][2] = fmaf(x4.y, w4.z, acc[1][2]);
    acc[1][3] = fmaf(x4.y, w4.w, acc[1][3]);
    acc[2][0] = fmaf(x4.z, w4.x, acc[2][0]);
    acc[2][1] = fmaf(x4.z, w4.y, acc[2][1]);
    acc[2][2] = fmaf(x4.z, w4.z, acc[2][2]);
    acc[2][3] = fmaf(x4.z, w4.w, acc[2][3]);
    acc[3][0] = fmaf(x4.w, w4.x, acc[3][0]);
    acc[3][1] = fmaf(x4.w, w4.y, acc[3][1]);
    acc[3][2] = fmaf(x4.w, w4.z, acc[3][2]);
    acc[3][3] = fmaf(x4.w, w4.w, acc[3][3]);
  }
  const size_t base = ((size_t)kb*32 + tr*4)*1024 + j0 + tj*4;
#pragma unroll
  for (int i = 0; i < 4; ++i)
    *(float4*)(part + base + (size_t)i*1024) = make_float4(acc[i][0], acc[i][1], acc[i][2], acc[i][3]);
}

// reduce batched Wv partials -> xs[b][t+1] (+bv). grid 896, block 256.
__global__ __launch_bounds__(256) void mv2xs(
    const float* __restrict__ part, const float* __restrict__ bv, float* __restrict__ xs)
{
  int idx = blockIdx.x*256 + threadIdx.x;   // 224*1024
  int r = idx >> 10, j = idx & 1023;
  int t = r >> 5, b = r & 31;
  const size_t stride = (size_t)224*1024;
  float s = bv[j];
#pragma unroll
  for (int kb = 0; kb < 4; ++kb) s += part[(size_t)kb*stride + idx];
  xs[(((size_t)b*Tn) + t + 1)*1024 + j] = s;
}

// ---------------- stage-2 kernels ----------------

__global__ __launch_bounds__(512) void scores2_kernel(
    const float* __restrict__ hidden, const float* __restrict__ xk2, float* __restrict__ sc)
{
  int b = blockIdx.y, p = blockIdx.x;
  int lane = threadIdx.x & 63, w = threadIdx.x >> 6;
  int t0 = (w & 3) * 2, rh = w >> 2;
  const float4* qa = (const float4*)(xk2 + ((size_t)b*Tn + t0  )*Hn) + lane;
  const float4* qb = (const float4*)(xk2 + ((size_t)b*Tn + t0+1)*Hn) + lane;
  float4 a0=qa[0], a1=qa[64], a2=qa[128], a3=qa[192];
  float4 c0=qb[0], c1=qb[64], c2=qb[128], c3=qb[192];
#pragma unroll 2
  for (int r = 0; r < 8; ++r){
    int s = p*16 + rh*8 + r;
    const float4* row = (const float4*)(hidden + ((size_t)s*Bn + b)*Hn) + lane;
    float4 v0=row[0], v1=row[64], v2=row[128], v3=row[192];
    float d0 = wsum(dot16(a0,a1,a2,a3, v0,v1,v2,v3));
    float d1 = wsum(dot16(c0,c1,c2,c3, v0,v1,v2,v3));
    if (lane == 0){
      sc[((size_t)b*Tn + t0  )*Sn + s] = d0;
      sc[((size_t)b*Tn + t0+1)*Sn + s] = d1;
    }
  }
}

__global__ __launch_bounds__(512) void softmax512(float* __restrict__ sc){
  int row = blockIdx.x, tid = threadIdx.x, lane = tid & 63, w = tid >> 6;
  float v = sc[(size_t)row*Sn + tid];
  float mx = v;
#pragma unroll
  for (int off = 32; off; off >>= 1) mx = fmaxf(mx, __shfl_xor(mx, off));
  __shared__ float sm[8], ss[8];
  if (lane == 0) sm[w] = mx;
  __syncthreads();
  mx = sm[0];
#pragma unroll
  for (int i = 1; i < 8; ++i) mx = fmaxf(mx, sm[i]);
  float e = __expf(v - mx);
  float s = e;
#pragma unroll
  for (int off = 32; off; off >>= 1) s += __shfl_xor(s, off);
  if (lane == 0) ss[w] = s;
  __syncthreads();
  float tot = 0.f;
#pragma unroll
  for (int i = 0; i < 8; ++i) tot += ss[i];
  sc[(size_t)row*Sn + tid] = e / tot;
}

__global__ __launch_bounds__(512) void ctx2p(
    const float* __restrict__ hidden, const float* __restrict__ attn, float* __restrict__ part)
{
  int hc = blockIdx.x, sc = blockIdx.y, b = blockIdx.z;
  int tid = threadIdx.x, hloc = tid & 127, tg = tid >> 7;
  __shared__ float al[Tn*128];
  for (int idx = tid; idx < Tn*128; idx += 512){
    int t = idx >> 7, si = idx & 127;
    al[idx] = attn[((size_t)b*Tn + t)*Sn + sc*128 + si];
  }
  __syncthreads();
  int h = hc*128 + hloc, t0 = tg*2;
  float acc0 = 0.f, acc1 = 0.f;
#pragma unroll 4
  for (int si = 0; si < 128; ++si){
    int s = sc*128 + si;
    float v = hidden[((size_t)s*Bn + b)*Hn + h];
    acc0 = fmaf(al[t0*128 + si],     v, acc0);
    acc1 = fmaf(al[(t0+1)*128 + si], v, acc1);
  }
  part[(((size_t)sc*Bn + b)*Tn + t0  )*Hn + h] = acc0;
  part[(((size_t)sc*Bn + b)*Tn + t0+1)*Hn + h] = acc1;
}

__global__ __launch_bounds__(256) void ctx2r(const float* __restrict__ part, float* __restrict__ out){
  int idx = blockIdx.x*256 + threadIdx.x;   // 262144
  out[idx] = part[idx] + part[262144 + idx] + part[524288 + idx] + part[786432 + idx];
}

// ---------------- LSTM: fused partial-reduce + pointwise ----------------
__global__ __launch_bounds__(256) void lstm_fused(
    const float* __restrict__ part, const float* __restrict__ b_ih,
    const float* __restrict__ b_hh, float* __restrict__ fq)
{
  int idx = blockIdx.x*256 + threadIdx.x;   // 32768
  int b = idx >> 10, h = idx & 1023;
  const size_t stride = (size_t)32*Gn;
  float gi = b_ih[h] + b_hh[h];
  float gg = b_ih[2048+h] + b_hh[2048+h];
  float go = b_ih[3072+h] + b_hh[3072+h];
  for (int kb = 0; kb < 16; ++kb){
    const float* pp = part + (size_t)kb*stride + (size_t)b*Gn;
    gi += pp[h]; gg += pp[2048+h]; go += pp[3072+h];
  }
  float si = 1.f/(1.f + __expf(-gi));
  float so = 1.f/(1.f + __expf(-go));
  float c  = si * tanhf(gg);
  fq[((size_t)b*(Tn+1) + Tn)*Hn + h] = so * tanhf(c);
}

// ---------------- host ----------------

extern "C" void kernel_launch(void* const* d_in, const int* in_sizes, int n_in,
                              void* d_out, int out_size, void* d_ws, size_t ws_size,
                              hipStream_t stream) {
  const float* hidden = (const float*)d_in[0];
  const float* nums   = (const float*)d_in[1];
  const float* pq     = (const float*)d_in[2];
  const float* Wk     = (const float*)d_in[3];
  const float* Wv     = (const float*)d_in[5];
  const float* bv     = (const float*)d_in[6];
  const float* Wk2    = (const float*)d_in[7];
  const float* Wv2    = (const float*)d_in[9];
  const float* bv2    = (const float*)d_in[10];
  const float* W_ih   = (const float*)d_in[11];
  const float* b_ih   = (const float*)d_in[13];
  const float* b_hh   = (const float*)d_in[14];

  float* out = (float*)d_out;
  float* fq  = out;                                   // (B, T+1, H)
  float* uh  = out + (size_t)Bn*(Tn+1)*Hn;            // (S+T, B, H)
  float* un  = uh + (size_t)(Sn+Tn)*Bn*Hn;            // (B, N+T, H)

  // ws layout (floats); high-water 7,474,176 floats = 29.9 MB
  // (ws_size proven >= 56 MB: R3's bf16 path, guarded at 56 MB, was active)
  float* ws    = (float*)d_ws;
  float* xs    = ws;                 // 262144
  float* ctxp  = ws + 262144;        // 524288 (B*16*H)
  float* mlp   = ws + 1310720;       // 512
  float* xk    = ws + 1312768;       // 32768
  float* xk2   = ws + 1345536;       // 262144
  float* sc2   = ws + 1607680;       // 131072
  float* ctx2v = ws + 1738752;       // 262144
  float* partX = ws + 2000896;       // 524288 (16*32*1024)
  float* partK = ws + 2525184;       // 524288
  float* WkT   = ws + 3049472;       // 1048576
  float* Wk2T  = ws + 4098048;       // 1048576
  float* WvT   = ws + 5146624;       // 1048576
  float* Dcomb = ws + 6195200;       // 1048576 (D[j][i] = sum_m Wk[m][j] Wv[m][i])
  float* ctxall= ws + 7243776;       // 229376 (7*32*1024 normalized ctx per step)
  float* dk    = ws + 7473152;       // 1024  (dk[j] = sum_m bv[m] Wk[m][j])
  float* partS = partX;              // stage-2 / batched-xs partials (spans partX+partK)
  float* c2part= partX;              // ctx2 split-s partials (same region, disjoint lifetime)
  float* partL = WkT;                // LSTM partials 16*32*4096 (WkT/Wk2T dead by then)

  transpose3<<<dim3(32,32,3), 256, 0, stream>>>(Wk, Wk2, Wv, WkT, Wk2T, WvT);
  prep<<<dim3(Nn+1, Bn), 256, 0, stream>>>((const float4*)nums, (const float4*)pq, (float4*)un, (float4*)xs);
  // one-time: D = Wk^T * Wv  (out[j][i] = sum_m WkT[j][m]*WvT[i][m]), KB=1 -> direct
  mv1<<<dim3(8,1,32), 256, 0, stream>>>(WkT, Hn, WvT, Dcomb, Hn, 16);
  dkv<<<256, 256, 0, stream>>>(bv, WkT, dk);

  // xk0 = Wk^T problem_q
  mv1<<<dim3(8,16,1), 256, 0, stream>>>(pq, Hn, WkT, partK, Hn, 1);
  mv2<<<128, 256, 0, stream>>>(partK, 32, 10, 16, nullptr, nullptr, xk, 0, 1);

  for (int t = 1; t < Tn; ++t){
    if (t == 1) attend9<1><<<dim3(16,Bn), 512, 0, stream>>>(hidden, xk, ctxp, mlp, uh);
    else        attend9<0><<<dim3(16,Bn), 512, 0, stream>>>(hidden, xk, ctxp, mlp, uh);
    float* ctxt = ctxall + (size_t)(t-1)*Bn*Hn;
    if (t < Tn-1){
      genw<1><<<dim3(8,16), 256, 0, stream>>>(ctxp, mlp, Dcomb, partX, ctxt);
      mv2<<<128, 256, 0, stream>>>(partX, 32, 10, 16, dk, nullptr, xk, 0, 1);
    } else {
      genw<0><<<dim3(1,16), 256, 0, stream>>>(ctxp, mlp, Dcomb, partX, ctxt);
    }
  }

  // xs[:,1..7,:] = ctxall @ Wv^T + bv  (batched, off critical path until here)
  mv1<<<dim3(8,4,7), 256, 0, stream>>>(ctxall, Hn, Wv, partS, Hn, 4);
  mv2xs<<<896, 256, 0, stream>>>(partS, bv, xs);

  // stage 2
  mv1<<<dim3(8,4,8), 256, 0, stream>>>(xs, Hn, Wk2T, partS, Hn, 4);
  mv2<<<1024, 256, 0, stream>>>(partS, 256, 10, 4, nullptr, nullptr, xk2, 0, 1);
  scores2_kernel<<<dim3(32, Bn), 512, 0, stream>>>(hidden, xk2, sc2);
  softmax512<<<Bn*Tn, 512, 0, stream>>>(sc2);
  ctx2p<<<dim3(8, 4, Bn), 512, 0, stream>>>(hidden, sc2, c2part);
  ctx2r<<<1024, 256, 0, stream>>>(c2part, ctx2v);
  mv1<<<dim3(8,4,8), 256, 0, stream>>>(ctx2v, Hn, Wv2, partS, Hn, 4);
  mv2<<<1024, 256, 0, stream>>>(partS, 256, 10, 4, bv2, nullptr, fq, 3, Tn+1);

  // LSTM step 1 (partials overlay WkT/Wk2T -- dead by now)
  mv1<<<dim3(32,16,1), 256, 0, stream>>>(fq, (Tn+1)*Hn, W_ih, partL, Gn, 1);
  lstm_fused<<<128, 256, 0, stream>>>(partL, b_ih, b_hh, fq);

  finalize_xs<<<dim3(Tn, Bn), 256, 0, stream>>>((const float4*)xs, (float4*)uh, (float4*)un);
}

// Round 12
// 356.966 us; speedup vs baseline: 1.4086x; 1.0637x over previous
//
#include <hip/hip_runtime.h>
#include <math.h>

#define Bn 32
#define Sn 512
#define Hn 1024
#define Tn 8
#define Nn 16
#define Gn 4096

__device__ __forceinline__ float wsum(float v){
#pragma unroll
  for (int off = 32; off; off >>= 1) v += __shfl_xor(v, off);
  return v;
}

__device__ __forceinline__ float dot16(float4 a0, float4 a1, float4 a2, float4 a3,
                                       float4 v0, float4 v1, float4 v2, float4 v3){
  float d = a0.x*v0.x + a0.y*v0.y + a0.z*v0.z + a0.w*v0.w;
  d += a1.x*v1.x + a1.y*v1.y + a1.z*v1.z + a1.w*v1.w;
  d += a2.x*v2.x + a2.y*v2.y + a2.z*v2.z + a2.w*v2.w;
  d += a3.x*v3.x + a3.y*v3.y + a3.z*v3.z + a3.w*v3.w;
  return d;
}

// ---------------- utility kernels ----------------

// three weight transposes in one launch. grid (32,32,3)
__global__ __launch_bounds__(256) void transpose3(
    const float* __restrict__ Wk, const float* __restrict__ Wk2, const float* __restrict__ Wv,
    float* __restrict__ WkT, float* __restrict__ Wk2T, float* __restrict__ WvT){
  __shared__ float tile[32][33];
  const float* in  = (blockIdx.z == 0) ? Wk  : (blockIdx.z == 1) ? Wk2  : Wv;
  float*       outp= (blockIdx.z == 0) ? WkT : (blockIdx.z == 1) ? Wk2T : WvT;
  int tx = threadIdx.x & 31, ty = threadIdx.x >> 5;
  int c0 = blockIdx.x * 32, r0 = blockIdx.y * 32;
#pragma unroll
  for (int k = 0; k < 4; ++k)
    tile[ty + 8*k][tx] = in[(size_t)(r0 + ty + 8*k) * Hn + c0 + tx];
  __syncthreads();
#pragma unroll
  for (int k = 0; k < 4; ++k)
    outp[(size_t)(c0 + ty + 8*k) * Hn + r0 + tx] = tile[tx][ty + 8*k];
}

__global__ __launch_bounds__(256) void prep(
    const float4* __restrict__ nums, const float4* __restrict__ pq,
    float4* __restrict__ un, float4* __restrict__ xs){
  int n = blockIdx.x, b = blockIdx.y;
  if (n < Nn) un[((size_t)b*(Nn+Tn) + n)*256 + threadIdx.x] = nums[((size_t)b*Nn + n)*256 + threadIdx.x];
  else        xs[((size_t)b*Tn)*256 + threadIdx.x] = pq[(size_t)b*256 + threadIdx.x];
}

__global__ __launch_bounds__(256) void finalize_xs(const float4* __restrict__ xs, float4* __restrict__ uh, float4* __restrict__ un){
  int t = blockIdx.x, b = blockIdx.y;
  float4 v = xs[((size_t)b*Tn + t)*256 + threadIdx.x];
  uh[(((size_t)(Sn + t))*Bn + b)*256 + threadIdx.x] = v;
  un[((size_t)b*(Nn+Tn) + Nn + t)*256 + threadIdx.x] = v;
}

// dk[j] = dot(bv, WkT[j]) over 1024. grid 256, block 256 (4 waves, 1 j each).
__global__ __launch_bounds__(256) void dkv(
    const float* __restrict__ bv, const float* __restrict__ WkT, float* __restrict__ dk)
{
  int lane = threadIdx.x & 63, w = threadIdx.x >> 6;
  int j = blockIdx.x*4 + w;
  const float4* rp = (const float4*)(WkT + (size_t)j*Hn) + lane;
  const float4* bp = (const float4*)bv + lane;
  float4 v0=rp[0], v1=rp[64], v2=rp[128], v3=rp[192];
  float4 b0=bp[0], b1=bp[64], b2=bp[128], b3=bp[192];
  float d = wsum(dot16(b0,b1,b2,b3, v0,v1,v2,v3));
  if (lane == 0) dk[j] = d;
}

// ---------------- attention (gen loop): 4 rows/wave, batched coalesced loads
template<int FIRST>
__global__ __launch_bounds__(512, 4) void attend9(
    const float* __restrict__ hidden, const float* __restrict__ xk,
    float* __restrict__ ctxp, float* __restrict__ mlp, float* __restrict__ uh)
{
  const int b = blockIdx.y, p = blockIdx.x;
  const int tid = threadIdx.x, lane = tid & 63, w = tid >> 6;
  __shared__ float sM[8], sL[8];
  __shared__ float sacc[8*1024];

  const float4* xp = (const float4*)(xk + (size_t)b*Hn) + lane;
  float4 q0 = xp[0], q1 = xp[64], q2 = xp[128], q3 = xp[192];

  const int s0 = p*32 + w*4;
  size_t ro[4];
#pragma unroll
  for (int i = 0; i < 4; ++i) ro[i] = ((size_t)(s0+i)*Bn + b)*Hn;
  float4 u[4][4];
#pragma unroll
  for (int i = 0; i < 4; ++i){
    const float4* rp = (const float4*)(hidden + ro[i]) + lane;
    u[i][0]=rp[0]; u[i][1]=rp[64]; u[i][2]=rp[128]; u[i][3]=rp[192];
  }
  if (FIRST){
#pragma unroll
    for (int i = 0; i < 4; ++i){
      float4* wp = (float4*)(uh + ro[i]) + lane;
      wp[0]=u[i][0]; wp[64]=u[i][1]; wp[128]=u[i][2]; wp[192]=u[i][3];
    }
  }
  float d[4];
#pragma unroll
  for (int i = 0; i < 4; ++i) d[i] = dot16(q0,q1,q2,q3, u[i][0],u[i][1],u[i][2],u[i][3]);
#pragma unroll
  for (int off = 32; off; off >>= 1){
#pragma unroll
    for (int i = 0; i < 4; ++i) d[i] += __shfl_xor(d[i], off);
  }
  float mw = fmaxf(fmaxf(d[0], d[1]), fmaxf(d[2], d[3]));
  sM[w] = mw;
  __syncthreads();
  float M = sM[0];
#pragma unroll
  for (int i = 1; i < 8; ++i) M = fmaxf(M, sM[i]);
  float wi[4], lw = 0.f;
#pragma unroll
  for (int i = 0; i < 4; ++i){ wi[i] = __expf(d[i] - M); lw += wi[i]; }
  float4 a0, a1, a2, a3;
  a0 = make_float4(wi[0]*u[0][0].x, wi[0]*u[0][0].y, wi[0]*u[0][0].z, wi[0]*u[0][0].w);
  a1 = make_float4(wi[0]*u[0][1].x, wi[0]*u[0][1].y, wi[0]*u[0][1].z, wi[0]*u[0][1].w);
  a2 = make_float4(wi[0]*u[0][2].x, wi[0]*u[0][2].y, wi[0]*u[0][2].z, wi[0]*u[0][2].w);
  a3 = make_float4(wi[0]*u[0][3].x, wi[0]*u[0][3].y, wi[0]*u[0][3].z, wi[0]*u[0][3].w);
#pragma unroll
  for (int i = 1; i < 4; ++i){
    a0.x = fmaf(wi[i], u[i][0].x, a0.x); a0.y = fmaf(wi[i], u[i][0].y, a0.y);
    a0.z = fmaf(wi[i], u[i][0].z, a0.z); a0.w = fmaf(wi[i], u[i][0].w, a0.w);
    a1.x = fmaf(wi[i], u[i][1].x, a1.x); a1.y = fmaf(wi[i], u[i][1].y, a1.y);
    a1.z = fmaf(wi[i], u[i][1].z, a1.z); a1.w = fmaf(wi[i], u[i][1].w, a1.w);
    a2.x = fmaf(wi[i], u[i][2].x, a2.x); a2.y = fmaf(wi[i], u[i][2].y, a2.y);
    a2.z = fmaf(wi[i], u[i][2].z, a2.z); a2.w = fmaf(wi[i], u[i][2].w, a2.w);
    a3.x = fmaf(wi[i], u[i][3].x, a3.x); a3.y = fmaf(wi[i], u[i][3].y, a3.y);
    a3.z = fmaf(wi[i], u[i][3].z, a3.z); a3.w = fmaf(wi[i], u[i][3].w, a3.w);
  }
  {
    int sl0 = (lane*4 + 0) ^ (lane & 7);
    int sl1 = (lane*4 + 1) ^ (lane & 7);
    int sl2 = (lane*4 + 2) ^ (lane & 7);
    int sl3 = (lane*4 + 3) ^ (lane & 7);
    *(float4*)(sacc + w*1024 + sl0*4) = a0;
    *(float4*)(sacc + w*1024 + sl1*4) = a1;
    *(float4*)(sacc + w*1024 + sl2*4) = a2;
    *(float4*)(sacc + w*1024 + sl3*4) = a3;
  }
  if (lane == 0) sL[w] = lw;
  __syncthreads();
#pragma unroll
  for (int h0 = 0; h0 < 1024; h0 += 512){
    int c = h0 + tid;
    int k = c >> 8, l = (c >> 2) & 63, j = c & 3;
    int fo = ((((l << 2) + k) ^ (l & 7)) << 2) + j;
    float s = 0.f;
#pragma unroll
    for (int i = 0; i < 8; ++i) s += sacc[i*1024 + fo];
    ctxp[((size_t)b*16 + p)*1024 + c] = s;
  }
  if (tid == 0){
    float L = 0.f;
#pragma unroll
    for (int i = 0; i < 8; ++i) L += sL[i];
    mlp[((size_t)b*16 + p)*2]     = M;
    mlp[((size_t)b*16 + p)*2 + 1] = L;
  }
}

// ---------------- split-K register-tiled matvec ----------------
__global__ __launch_bounds__(256) void mv1(
    const float* __restrict__ X, int xstride,
    const float* __restrict__ M, float* __restrict__ part,
    int nj, int ktiles)
{
  __shared__ float wt[64*128];
  __shared__ float xl[64*32];
  const int t  = threadIdx.x;
  const int j0 = blockIdx.x * 128;
  const int kb = blockIdx.y;
  const int r0 = blockIdx.z * 32;
  const int R  = gridDim.z * 32;
  const int tj = t & 31, tr = t >> 5;
  float acc[4][4] = {{0.f,0.f,0.f,0.f},{0.f,0.f,0.f,0.f},{0.f,0.f,0.f,0.f},{0.f,0.f,0.f,0.f}};

  for (int kt = 0; kt < ktiles; ++kt){
    const int k0 = (kb*ktiles + kt)*64;
    __syncthreads();
    {
      int j = t >> 1;
      int kqb = (t & 1) * 8;
      const float* Mrow = M + (size_t)(j0 + j)*1024 + k0;
#pragma unroll
      for (int c = 0; c < 8; ++c){
        float4 v = *(const float4*)(Mrow + (kqb + c)*4);
        int kk = (kqb + c)*4;
        wt[(kk+0)*128 + j] = v.x;
        wt[(kk+1)*128 + j] = v.y;
        wt[(kk+2)*128 + j] = v.z;
        wt[(kk+3)*128 + j] = v.w;
      }
      int r = t >> 3;
      int kq0 = t & 7;
#pragma unroll
      for (int c = 0; c < 2; ++c){
        int kk = (kq0 + c*8)*4;
        float4 v = *(const float4*)(X + (size_t)(r0 + r)*xstride + k0 + kk);
        xl[(kk+0)*32 + r] = v.x;
        xl[(kk+1)*32 + r] = v.y;
        xl[(kk+2)*32 + r] = v.z;
        xl[(kk+3)*32 + r] = v.w;
      }
    }
    __syncthreads();
#pragma unroll 4
    for (int k = 0; k < 64; ++k){
      float4 w4 = *(const float4*)(wt + k*128 + tj*4);
      float4 x4 = *(const float4*)(xl + k*32  + tr*4);
      acc[0][0] = fmaf(x4.x, w4.x, acc[0][0]);
      acc[0][1] = fmaf(x4.x, w4.y, acc[0][1]);
      acc[0][2] = fmaf(x4.x, w4.z, acc[0][2]);
      acc[0][3] = fmaf(x4.x, w4.w, acc[0][3]);
      acc[1][0] = fmaf(x4.y, w4.x, acc[1][0]);
      acc[1][1] = fmaf(x4.y, w4.y, acc[1][1]);
      acc[1][2] = fmaf(x4.y, w4.z, acc[1][2]);
      acc[1][3] = fmaf(x4.y, w4.w, acc[1][3]);
      acc[2][0] = fmaf(x4.z, w4.x, acc[2][0]);
      acc[2][1] = fmaf(x4.z, w4.y, acc[2][1]);
      acc[2][2] = fmaf(x4.z, w4.z, acc[2][2]);
      acc[2][3] = fmaf(x4.z, w4.w, acc[2][3]);
      acc[3][0] = fmaf(x4.w, w4.x, acc[3][0]);
      acc[3][1] = fmaf(x4.w, w4.y, acc[3][1]);
      acc[3][2] = fmaf(x4.w, w4.z, acc[3][2]);
      acc[3][3] = fmaf(x4.w, w4.w, acc[3][3]);
    }
  }
  const size_t base = ((size_t)kb*R + r0 + tr*4)*nj + j0 + tj*4;
#pragma unroll
  for (int i = 0; i < 4; ++i)
    *(float4*)(part + base + (size_t)i*nj) = make_float4(acc[i][0], acc[i][1], acc[i][2], acc[i][3]);
}

__global__ __launch_bounds__(256) void mv2(
    const float* __restrict__ part, int R, int njshift, int KB,
    const float* __restrict__ b1, const float* __restrict__ b2,
    float* __restrict__ out, int rpgshift, int opg)
{
  int idx = blockIdx.x*256 + threadIdx.x;
  int nj = 1 << njshift;
  int r = idx >> njshift, j = idx & (nj - 1);
  float s = 0.f;
  if (b1) s += b1[j];
  if (b2) s += b2[j];
  size_t stride = (size_t)R << njshift;
  for (int kb = 0; kb < KB; ++kb) s += part[(size_t)kb*stride + idx];
  int orow = ((r >> rpgshift) * opg) + (r & ((1 << rpgshift) - 1));
  out[((size_t)orow << njshift) + j] = s;
}

// ---------------- genw: fused combine + D matvec; side-writes normalized ctx
// FULL=1: grid (8,16); FULL=0 (combine-only, t=Tn-1): grid (1,16).
template<int FULL>
__global__ __launch_bounds__(256) void genw(
    const float* __restrict__ ctxp, const float* __restrict__ mlp,
    const float* __restrict__ D, float* __restrict__ part, float* __restrict__ ctxout)
{
  __shared__ float wt[64*128];
  __shared__ float xl[64*32];
  const int t  = threadIdx.x;
  const int j0 = blockIdx.x * 128;
  const int kb = blockIdx.y;
  const int k0 = kb*64;
  const int tj = t & 31, tr = t >> 5;

  if (FULL){
    int j = t >> 1;
    int kqb = (t & 1) * 8;
    const float* Mrow = D + (size_t)(j0 + j)*1024 + k0;
#pragma unroll
    for (int c = 0; c < 8; ++c){
      float4 v = *(const float4*)(Mrow + (kqb + c)*4);
      int kk = (kqb + c)*4;
      wt[(kk+0)*128 + j] = v.x;
      wt[(kk+1)*128 + j] = v.y;
      wt[(kk+2)*128 + j] = v.z;
      wt[(kk+3)*128 + j] = v.w;
    }
  }
  {
    int b = t >> 3, kk = (t & 7)*8;
    float mx = -1e30f;
#pragma unroll
    for (int i = 0; i < 16; ++i) mx = fmaxf(mx, mlp[((size_t)b*16 + i)*2]);
    float L = 0.f;
    float a8[8] = {0.f,0.f,0.f,0.f,0.f,0.f,0.f,0.f};
#pragma unroll 4
    for (int i = 0; i < 16; ++i){
      float m = mlp[((size_t)b*16 + i)*2];
      float l = mlp[((size_t)b*16 + i)*2 + 1];
      float we = __expf(m - mx);
      L = fmaf(l, we, L);
      const float* cp = ctxp + ((size_t)b*16 + i)*1024 + k0 + kk;
      float4 u0 = *(const float4*)cp;
      float4 u1 = *(const float4*)(cp + 4);
      a8[0] = fmaf(we, u0.x, a8[0]); a8[1] = fmaf(we, u0.y, a8[1]);
      a8[2] = fmaf(we, u0.z, a8[2]); a8[3] = fmaf(we, u0.w, a8[3]);
      a8[4] = fmaf(we, u1.x, a8[4]); a8[5] = fmaf(we, u1.y, a8[5]);
      a8[6] = fmaf(we, u1.z, a8[6]); a8[7] = fmaf(we, u1.w, a8[7]);
    }
    float inv = 1.f / L;
#pragma unroll
    for (int q = 0; q < 8; ++q){
      float c = a8[q]*inv;
      if (FULL) xl[(kk + q)*32 + b] = c;
      if (!FULL || blockIdx.x == 0) ctxout[(size_t)b*1024 + k0 + kk + q] = c;
    }
  }
  if (!FULL) return;
  __syncthreads();
  float acc[4][4] = {{0.f,0.f,0.f,0.f},{0.f,0.f,0.f,0.f},{0.f,0.f,0.f,0.f},{0.f,0.f,0.f,0.f}};
#pragma unroll 4
  for (int k = 0; k < 64; ++k){
    float4 w4 = *(const float4*)(wt + k*128 + tj*4);
    float4 x4 = *(const float4*)(xl + k*32  + tr*4);
    acc[0][0] = fmaf(x4.x, w4.x, acc[0][0]);
    acc[0][1] = fmaf(x4.x, w4.y, acc[0][1]);
    acc[0][2] = fmaf(x4.x, w4.z, acc[0][2]);
    acc[0][3] = fmaf(x4.x, w4.w, acc[0][3]);
    acc[1][0] = fmaf(x4.y, w4.x, acc[1][0]);
    acc[1][1] = fmaf(x4.y, w4.y, acc[1][1]);
    acc[1][2] = fmaf(x4.y, w4.z, acc[1][2]);
    acc[1][3] = fmaf(x4.y, w4.w, acc[1][3]);
    acc[2][0] = fmaf(x4.z, w4.x, acc[2][0]);
    acc[2][1] = fmaf(x4.z, w4.y, acc[2][1]);
    acc[2][2] = fmaf(x4.z, w4.z, acc[2][2]);
    acc[2][3] = fmaf(x4.z, w4.w, acc[2][3]);
    acc[3][0] = fmaf(x4.w, w4.x, acc[3][0]);
    acc[3][1] = fmaf(x4.w, w4.y, acc[3][1]);
    acc[3][2] = fmaf(x4.w, w4.z, acc[3][2]);
    acc[3][3] = fmaf(x4.w, w4.w, acc[3][3]);
  }
  const size_t base = ((size_t)kb*32 + tr*4)*1024 + j0 + tj*4;
#pragma unroll
  for (int i = 0; i < 4; ++i)
    *(float4*)(part + base + (size_t)i*1024) = make_float4(acc[i][0], acc[i][1], acc[i][2], acc[i][3]);
}

// reduce batched Wv partials -> xs[b][t+1] (+bv). KB=16, R=224. grid 896, block 256.
__global__ __launch_bounds__(256) void mv2xs(
    const float* __restrict__ part, const float* __restrict__ bv, float* __restrict__ xs)
{
  int idx = blockIdx.x*256 + threadIdx.x;   // 224*1024
  int r = idx >> 10, j = idx & 1023;
  int t = r >> 5, b = r & 31;
  const size_t stride = (size_t)224*1024;
  float s = bv[j];
#pragma unroll
  for (int kb = 0; kb < 16; ++kb) s += part[(size_t)kb*stride + idx];
  xs[(((size_t)b*Tn) + t + 1)*1024 + j] = s;
}

// ---------------- stage-2 kernels ----------------

__global__ __launch_bounds__(512) void scores2_kernel(
    const float* __restrict__ hidden, const float* __restrict__ xk2, float* __restrict__ sc)
{
  int b = blockIdx.y, p = blockIdx.x;
  int lane = threadIdx.x & 63, w = threadIdx.x >> 6;
  int t0 = (w & 3) * 2, rh = w >> 2;
  const float4* qa = (const float4*)(xk2 + ((size_t)b*Tn + t0  )*Hn) + lane;
  const float4* qb = (const float4*)(xk2 + ((size_t)b*Tn + t0+1)*Hn) + lane;
  float4 a0=qa[0], a1=qa[64], a2=qa[128], a3=qa[192];
  float4 c0=qb[0], c1=qb[64], c2=qb[128], c3=qb[192];
#pragma unroll 2
  for (int r = 0; r < 8; ++r){
    int s = p*16 + rh*8 + r;
    const float4* row = (const float4*)(hidden + ((size_t)s*Bn + b)*Hn) + lane;
    float4 v0=row[0], v1=row[64], v2=row[128], v3=row[192];
    float d0 = wsum(dot16(a0,a1,a2,a3, v0,v1,v2,v3));
    float d1 = wsum(dot16(c0,c1,c2,c3, v0,v1,v2,v3));
    if (lane == 0){
      sc[((size_t)b*Tn + t0  )*Sn + s] = d0;
      sc[((size_t)b*Tn + t0+1)*Sn + s] = d1;
    }
  }
}

__global__ __launch_bounds__(512) void softmax512(float* __restrict__ sc){
  int row = blockIdx.x, tid = threadIdx.x, lane = tid & 63, w = tid >> 6;
  float v = sc[(size_t)row*Sn + tid];
  float mx = v;
#pragma unroll
  for (int off = 32; off; off >>= 1) mx = fmaxf(mx, __shfl_xor(mx, off));
  __shared__ float sm[8], ss[8];
  if (lane == 0) sm[w] = mx;
  __syncthreads();
  mx = sm[0];
#pragma unroll
  for (int i = 1; i < 8; ++i) mx = fmaxf(mx, sm[i]);
  float e = __expf(v - mx);
  float s = e;
#pragma unroll
  for (int off = 32; off; off >>= 1) s += __shfl_xor(s, off);
  if (lane == 0) ss[w] = s;
  __syncthreads();
  float tot = 0.f;
#pragma unroll
  for (int i = 0; i < 8; ++i) tot += ss[i];
  sc[(size_t)row*Sn + tid] = e / tot;
}

__global__ __launch_bounds__(512) void ctx2p(
    const float* __restrict__ hidden, const float* __restrict__ attn, float* __restrict__ part)
{
  int hc = blockIdx.x, sc = blockIdx.y, b = blockIdx.z;
  int tid = threadIdx.x, hloc = tid & 127, tg = tid >> 7;
  __shared__ float al[Tn*128];
  for (int idx = tid; idx < Tn*128; idx += 512){
    int t = idx >> 7, si = idx & 127;
    al[idx] = attn[((size_t)b*Tn + t)*Sn + sc*128 + si];
  }
  __syncthreads();
  int h = hc*128 + hloc, t0 = tg*2;
  float acc0 = 0.f, acc1 = 0.f;
#pragma unroll 4
  for (int si = 0; si < 128; ++si){
    int s = sc*128 + si;
    float v = hidden[((size_t)s*Bn + b)*Hn + h];
    acc0 = fmaf(al[t0*128 + si],     v, acc0);
    acc1 = fmaf(al[(t0+1)*128 + si], v, acc1);
  }
  part[(((size_t)sc*Bn + b)*Tn + t0  )*Hn + h] = acc0;
  part[(((size_t)sc*Bn + b)*Tn + t0+1)*Hn + h] = acc1;
}

__global__ __launch_bounds__(256) void ctx2r(const float* __restrict__ part, float* __restrict__ out){
  int idx = blockIdx.x*256 + threadIdx.x;   // 262144
  out[idx] = part[idx] + part[262144 + idx] + part[524288 + idx] + part[786432 + idx];
}

// ---------------- LSTM: fused partial-reduce + pointwise ----------------
__global__ __launch_bounds__(256) void lstm_fused(
    const float* __restrict__ part, const float* __restrict__ b_ih,
    const float* __restrict__ b_hh, float* __restrict__ fq)
{
  int idx = blockIdx.x*256 + threadIdx.x;   // 32768
  int b = idx >> 10, h = idx & 1023;
  const size_t stride = (size_t)32*Gn;
  float gi = b_ih[h] + b_hh[h];
  float gg = b_ih[2048+h] + b_hh[2048+h];
  float go = b_ih[3072+h] + b_hh[3072+h];
  for (int kb = 0; kb < 16; ++kb){
    const float* pp = part + (size_t)kb*stride + (size_t)b*Gn;
    gi += pp[h]; gg += pp[2048+h]; go += pp[3072+h];
  }
  float si = 1.f/(1.f + __expf(-gi));
  float so = 1.f/(1.f + __expf(-go));
  float c  = si * tanhf(gg);
  fq[((size_t)b*(Tn+1) + Tn)*Hn + h] = so * tanhf(c);
}

// ---------------- host ----------------

extern "C" void kernel_launch(void* const* d_in, const int* in_sizes, int n_in,
                              void* d_out, int out_size, void* d_ws, size_t ws_size,
                              hipStream_t stream) {
  const float* hidden = (const float*)d_in[0];
  const float* nums   = (const float*)d_in[1];
  const float* pq     = (const float*)d_in[2];
  const float* Wk     = (const float*)d_in[3];
  const float* Wv     = (const float*)d_in[5];
  const float* bv     = (const float*)d_in[6];
  const float* Wk2    = (const float*)d_in[7];
  const float* Wv2    = (const float*)d_in[9];
  const float* bv2    = (const float*)d_in[10];
  const float* W_ih   = (const float*)d_in[11];
  const float* b_ih   = (const float*)d_in[13];
  const float* b_hh   = (const float*)d_in[14];

  float* out = (float*)d_out;
  float* fq  = out;                                   // (B, T+1, H)
  float* uh  = out + (size_t)Bn*(Tn+1)*Hn;            // (S+T, B, H)
  float* un  = uh + (size_t)(Sn+Tn)*Bn*Hn;            // (B, N+T, H)

  // ws layout (floats); high-water 11,668,480 floats = 46.7 MB
  // (ws_size proven >= 56 MB: R3's bf16 path, guarded at 56 MB, was active)
  float* ws    = (float*)d_ws;
  float* xs    = ws;                 // 262144
  float* ctxp  = ws + 262144;        // 524288 (B*16*H)
  float* mlp   = ws + 1310720;       // 512
  float* xk    = ws + 1312768;       // 32768
  float* xk2   = ws + 1345536;       // 262144
  float* sc2   = ws + 1607680;       // 131072
  float* ctx2v = ws + 1738752;       // 262144
  float* partX = ws + 2000896;       // 524288 (16*32*1024)
  float* partK = ws + 2525184;       // 524288
  float* WkT   = ws + 3049472;       // 1048576
  float* Wk2T  = ws + 4098048;       // 1048576
  float* WvT   = ws + 5146624;       // 1048576
  float* Dcomb = ws + 6195200;       // 1048576 (D[j][i] = sum_m Wk[m][j] Wv[m][i])
  float* ctxall= ws + 7243776;       // 229376 (7*32*1024 normalized ctx per step)
  float* dk    = ws + 7473152;       // 1024  (dk[j] = sum_m bv[m] Wk[m][j])
  float* Dparts= ws + 7474176;       // 4194304 (split-K partials: Dcomb KB=4, then 256-row mv KB=16)
  float* c2part= partX;              // ctx2 split-s partials (spans partX+partK, disjoint lifetime)
  float* partL = WkT;                // LSTM partials 16*32*4096 (WkT/Wk2T dead by then)

  transpose3<<<dim3(32,32,3), 256, 0, stream>>>(Wk, Wk2, Wv, WkT, Wk2T, WvT);
  prep<<<dim3(Nn+1, Bn), 256, 0, stream>>>((const float4*)nums, (const float4*)pq, (float4*)un, (float4*)xs);
  // one-time: D = Wk^T * Wv -- split-K KB=4 (1024 blocks, 4/CU) + reduce
  mv1<<<dim3(8,4,32), 256, 0, stream>>>(WkT, Hn, WvT, Dparts, Hn, 4);
  mv2<<<4096, 256, 0, stream>>>(Dparts, 1024, 10, 4, nullptr, nullptr, Dcomb, 0, 1);
  dkv<<<256, 256, 0, stream>>>(bv, WkT, dk);

  // xk0 = Wk^T problem_q
  mv1<<<dim3(8,16,1), 256, 0, stream>>>(pq, Hn, WkT, partK, Hn, 1);
  mv2<<<128, 256, 0, stream>>>(partK, 32, 10, 16, nullptr, nullptr, xk, 0, 1);

  for (int t = 1; t < Tn; ++t){
    if (t == 1) attend9<1><<<dim3(16,Bn), 512, 0, stream>>>(hidden, xk, ctxp, mlp, uh);
    else        attend9<0><<<dim3(16,Bn), 512, 0, stream>>>(hidden, xk, ctxp, mlp, uh);
    float* ctxt = ctxall + (size_t)(t-1)*Bn*Hn;
    if (t < Tn-1){
      genw<1><<<dim3(8,16), 256, 0, stream>>>(ctxp, mlp, Dcomb, partX, ctxt);
      mv2<<<128, 256, 0, stream>>>(partX, 32, 10, 16, dk, nullptr, xk, 0, 1);
    } else {
      genw<0><<<dim3(1,16), 256, 0, stream>>>(ctxp, mlp, Dcomb, partX, ctxt);
    }
  }

  // xs[:,1..7,:] = ctxall @ Wv^T + bv  (batched; KB=16 -> 896 blocks)
  mv1<<<dim3(8,16,7), 256, 0, stream>>>(ctxall, Hn, Wv, Dparts, Hn, 1);
  mv2xs<<<896, 256, 0, stream>>>(Dparts, bv, xs);

  // stage 2 (256-row matvecs at KB=16 -> 1024 blocks each)
  mv1<<<dim3(8,16,8), 256, 0, stream>>>(xs, Hn, Wk2T, Dparts, Hn, 1);
  mv2<<<1024, 256, 0, stream>>>(Dparts, 256, 10, 16, nullptr, nullptr, xk2, 0, 1);
  scores2_kernel<<<dim3(32, Bn), 512, 0, stream>>>(hidden, xk2, sc2);
  softmax512<<<Bn*Tn, 512, 0, stream>>>(sc2);
  ctx2p<<<dim3(8, 4, Bn), 512, 0, stream>>>(hidden, sc2, c2part);
  ctx2r<<<1024, 256, 0, stream>>>(c2part, ctx2v);
  mv1<<<dim3(8,16,8), 256, 0, stream>>>(ctx2v, Hn, Wv2, Dparts, Hn, 1);
  mv2<<<1024, 256, 0, stream>>>(Dparts, 256, 10, 16, bv2, nullptr, fq, 3, Tn+1);

  // LSTM step 1 (partials overlay WkT/Wk2T -- dead by now)
  mv1<<<dim3(32,16,1), 256, 0, stream>>>(fq, (Tn+1)*Hn, W_ih, partL, Gn, 1);
  lstm_fused<<<128, 256, 0, stream>>>(partL, b_ih, b_hh, fq);

  finalize_xs<<<dim3(Tn, Bn), 256, 0, stream>>>((const float4*)xs, (float4*)uh, (float4*)un);
}

// Round 13
// 339.047 us; speedup vs baseline: 1.4831x; 1.0528x over previous
//
#include <hip/hip_runtime.h>
#include <math.h>

#define Bn 32
#define Sn 512
#define Hn 1024
#define Tn 8
#define Nn 16
#define Gn 4096

__device__ __forceinline__ float wsum(float v){
#pragma unroll
  for (int off = 32; off; off >>= 1) v += __shfl_xor(v, off);
  return v;
}

__device__ __forceinline__ float dot16(float4 a0, float4 a1, float4 a2, float4 a3,
                                       float4 v0, float4 v1, float4 v2, float4 v3){
  float d = a0.x*v0.x + a0.y*v0.y + a0.z*v0.z + a0.w*v0.w;
  d += a1.x*v1.x + a1.y*v1.y + a1.z*v1.z + a1.w*v1.w;
  d += a2.x*v2.x + a2.y*v2.y + a2.z*v2.z + a2.w*v2.w;
  d += a3.x*v3.x + a3.y*v3.y + a3.z*v3.z + a3.w*v3.w;
  return d;
}

// ---------------- utility kernels ----------------

// three weight transposes in one launch. grid (32,32,3)
__global__ __launch_bounds__(256) void transpose3(
    const float* __restrict__ Wk, const float* __restrict__ Wk2, const float* __restrict__ Wv,
    float* __restrict__ WkT, float* __restrict__ Wk2T, float* __restrict__ WvT){
  __shared__ float tile[32][33];
  const float* in  = (blockIdx.z == 0) ? Wk  : (blockIdx.z == 1) ? Wk2  : Wv;
  float*       outp= (blockIdx.z == 0) ? WkT : (blockIdx.z == 1) ? Wk2T : WvT;
  int tx = threadIdx.x & 31, ty = threadIdx.x >> 5;
  int c0 = blockIdx.x * 32, r0 = blockIdx.y * 32;
#pragma unroll
  for (int k = 0; k < 4; ++k)
    tile[ty + 8*k][tx] = in[(size_t)(r0 + ty + 8*k) * Hn + c0 + tx];
  __syncthreads();
#pragma unroll
  for (int k = 0; k < 4; ++k)
    outp[(size_t)(c0 + ty + 8*k) * Hn + r0 + tx] = tile[tx][ty + 8*k];
}

__global__ __launch_bounds__(256) void prep(
    const float4* __restrict__ nums, const float4* __restrict__ pq,
    float4* __restrict__ un, float4* __restrict__ xs){
  int n = blockIdx.x, b = blockIdx.y;
  if (n < Nn) un[((size_t)b*(Nn+Tn) + n)*256 + threadIdx.x] = nums[((size_t)b*Nn + n)*256 + threadIdx.x];
  else        xs[((size_t)b*Tn)*256 + threadIdx.x] = pq[(size_t)b*256 + threadIdx.x];
}

__global__ __launch_bounds__(256) void finalize_xs(const float4* __restrict__ xs, float4* __restrict__ uh, float4* __restrict__ un){
  int t = blockIdx.x, b = blockIdx.y;
  float4 v = xs[((size_t)b*Tn + t)*256 + threadIdx.x];
  uh[(((size_t)(Sn + t))*Bn + b)*256 + threadIdx.x] = v;
  un[((size_t)b*(Nn+Tn) + Nn + t)*256 + threadIdx.x] = v;
}

// dk[j] = dot(bv, WkT[j]) over 1024. grid 256, block 256 (4 waves, 1 j each).
__global__ __launch_bounds__(256) void dkv(
    const float* __restrict__ bv, const float* __restrict__ WkT, float* __restrict__ dk)
{
  int lane = threadIdx.x & 63, w = threadIdx.x >> 6;
  int j = blockIdx.x*4 + w;
  const float4* rp = (const float4*)(WkT + (size_t)j*Hn) + lane;
  const float4* bp = (const float4*)bv + lane;
  float4 v0=rp[0], v1=rp[64], v2=rp[128], v3=rp[192];
  float4 b0=bp[0], b1=bp[64], b2=bp[128], b3=bp[192];
  float d = wsum(dot16(b0,b1,b2,b3, v0,v1,v2,v3));
  if (lane == 0) dk[j] = d;
}

// ---------------- attention (gen loop): q-reduce folded in ----------------
// grid (16, B), block 512 = 8 waves x 4 rows, 512 blocks (2/CU).
// Hidden row loads are ISSUED FIRST; q is then built in LDS by summing the
// 16 split-K partials (+ optional dk bias) -- load latency hides under the
// q-build sweep, and the per-step mv2 launch disappears. 16 partials/b out.
// FIRST also emits uh (folds the 64MB hidden copy).
template<int FIRST>
__global__ __launch_bounds__(512, 4) void attend10(
    const float* __restrict__ hidden, const float* __restrict__ partq,
    const float* __restrict__ dk,
    float* __restrict__ ctxp, float* __restrict__ mlp, float* __restrict__ uh)
{
  const int b = blockIdx.y, p = blockIdx.x;
  const int tid = threadIdx.x, lane = tid & 63, w = tid >> 6;
  __shared__ float xq[1024];
  __shared__ float sM[8], sL[8];
  __shared__ float sacc[8*1024];

  // issue all 16 hidden row loads first (coalesced: lane l -> float4 {l,l+64,l+128,l+192})
  const int s0 = p*32 + w*4;
  size_t ro[4];
#pragma unroll
  for (int i = 0; i < 4; ++i) ro[i] = ((size_t)(s0+i)*Bn + b)*Hn;
  float4 u[4][4];
#pragma unroll
  for (int i = 0; i < 4; ++i){
    const float4* rp = (const float4*)(hidden + ro[i]) + lane;
    u[i][0]=rp[0]; u[i][1]=rp[64]; u[i][2]=rp[128]; u[i][3]=rp[192];
  }

  // q[c] = (dk ? dk[c] : 0) + sum_i partq[(i*Bn+b)*1024 + c]
#pragma unroll
  for (int h0 = 0; h0 < 1024; h0 += 512){
    int c = h0 + tid;
    float s = dk ? dk[c] : 0.f;
#pragma unroll
    for (int i = 0; i < 16; ++i) s += partq[((size_t)(i*Bn + b))*1024 + c];
    xq[c] = s;
  }
  if (FIRST){
#pragma unroll
    for (int i = 0; i < 4; ++i){
      float4* wp = (float4*)(uh + ro[i]) + lane;
      wp[0]=u[i][0]; wp[64]=u[i][1]; wp[128]=u[i][2]; wp[192]=u[i][3];
    }
  }
  __syncthreads();
  const float4* xp = (const float4*)xq + lane;
  float4 q0 = xp[0], q1 = xp[64], q2 = xp[128], q3 = xp[192];

  float d[4];
#pragma unroll
  for (int i = 0; i < 4; ++i) d[i] = dot16(q0,q1,q2,q3, u[i][0],u[i][1],u[i][2],u[i][3]);
#pragma unroll
  for (int off = 32; off; off >>= 1){
#pragma unroll
    for (int i = 0; i < 4; ++i) d[i] += __shfl_xor(d[i], off);
  }
  float mw = fmaxf(fmaxf(d[0], d[1]), fmaxf(d[2], d[3]));
  sM[w] = mw;
  __syncthreads();
  float M = sM[0];
#pragma unroll
  for (int i = 1; i < 8; ++i) M = fmaxf(M, sM[i]);
  float wi[4], lw = 0.f;
#pragma unroll
  for (int i = 0; i < 4; ++i){ wi[i] = __expf(d[i] - M); lw += wi[i]; }
  float4 a0, a1, a2, a3;
  a0 = make_float4(wi[0]*u[0][0].x, wi[0]*u[0][0].y, wi[0]*u[0][0].z, wi[0]*u[0][0].w);
  a1 = make_float4(wi[0]*u[0][1].x, wi[0]*u[0][1].y, wi[0]*u[0][1].z, wi[0]*u[0][1].w);
  a2 = make_float4(wi[0]*u[0][2].x, wi[0]*u[0][2].y, wi[0]*u[0][2].z, wi[0]*u[0][2].w);
  a3 = make_float4(wi[0]*u[0][3].x, wi[0]*u[0][3].y, wi[0]*u[0][3].z, wi[0]*u[0][3].w);
#pragma unroll
  for (int i = 1; i < 4; ++i){
    a0.x = fmaf(wi[i], u[i][0].x, a0.x); a0.y = fmaf(wi[i], u[i][0].y, a0.y);
    a0.z = fmaf(wi[i], u[i][0].z, a0.z); a0.w = fmaf(wi[i], u[i][0].w, a0.w);
    a1.x = fmaf(wi[i], u[i][1].x, a1.x); a1.y = fmaf(wi[i], u[i][1].y, a1.y);
    a1.z = fmaf(wi[i], u[i][1].z, a1.z); a1.w = fmaf(wi[i], u[i][1].w, a1.w);
    a2.x = fmaf(wi[i], u[i][2].x, a2.x); a2.y = fmaf(wi[i], u[i][2].y, a2.y);
    a2.z = fmaf(wi[i], u[i][2].z, a2.z); a2.w = fmaf(wi[i], u[i][2].w, a2.w);
    a3.x = fmaf(wi[i], u[i][3].x, a3.x); a3.y = fmaf(wi[i], u[i][3].y, a3.y);
    a3.z = fmaf(wi[i], u[i][3].z, a3.z); a3.w = fmaf(wi[i], u[i][3].w, a3.w);
  }
  {
    int sl0 = (lane*4 + 0) ^ (lane & 7);
    int sl1 = (lane*4 + 1) ^ (lane & 7);
    int sl2 = (lane*4 + 2) ^ (lane & 7);
    int sl3 = (lane*4 + 3) ^ (lane & 7);
    *(float4*)(sacc + w*1024 + sl0*4) = a0;
    *(float4*)(sacc + w*1024 + sl1*4) = a1;
    *(float4*)(sacc + w*1024 + sl2*4) = a2;
    *(float4*)(sacc + w*1024 + sl3*4) = a3;
  }
  if (lane == 0) sL[w] = lw;
  __syncthreads();
#pragma unroll
  for (int h0 = 0; h0 < 1024; h0 += 512){
    int c = h0 + tid;
    int k = c >> 8, l = (c >> 2) & 63, j = c & 3;
    int fo = ((((l << 2) + k) ^ (l & 7)) << 2) + j;
    float s = 0.f;
#pragma unroll
    for (int i = 0; i < 8; ++i) s += sacc[i*1024 + fo];
    ctxp[((size_t)b*16 + p)*1024 + c] = s;
  }
  if (tid == 0){
    float L = 0.f;
#pragma unroll
    for (int i = 0; i < 8; ++i) L += sL[i];
    mlp[((size_t)b*16 + p)*2]     = M;
    mlp[((size_t)b*16 + p)*2 + 1] = L;
  }
}

// ---------------- split-K register-tiled matvec ----------------
__global__ __launch_bounds__(256) void mv1(
    const float* __restrict__ X, int xstride,
    const float* __restrict__ M, float* __restrict__ part,
    int nj, int ktiles)
{
  __shared__ float wt[64*128];
  __shared__ float xl[64*32];
  const int t  = threadIdx.x;
  const int j0 = blockIdx.x * 128;
  const int kb = blockIdx.y;
  const int r0 = blockIdx.z * 32;
  const int R  = gridDim.z * 32;
  const int tj = t & 31, tr = t >> 5;
  float acc[4][4] = {{0.f,0.f,0.f,0.f},{0.f,0.f,0.f,0.f},{0.f,0.f,0.f,0.f},{0.f,0.f,0.f,0.f}};

  for (int kt = 0; kt < ktiles; ++kt){
    const int k0 = (kb*ktiles + kt)*64;
    __syncthreads();
    {
      int j = t >> 1;
      int kqb = (t & 1) * 8;
      const float* Mrow = M + (size_t)(j0 + j)*1024 + k0;
#pragma unroll
      for (int c = 0; c < 8; ++c){
        float4 v = *(const float4*)(Mrow + (kqb + c)*4);
        int kk = (kqb + c)*4;
        wt[(kk+0)*128 + j] = v.x;
        wt[(kk+1)*128 + j] = v.y;
        wt[(kk+2)*128 + j] = v.z;
        wt[(kk+3)*128 + j] = v.w;
      }
      int r = t >> 3;
      int kq0 = t & 7;
#pragma unroll
      for (int c = 0; c < 2; ++c){
        int kk = (kq0 + c*8)*4;
        float4 v = *(const float4*)(X + (size_t)(r0 + r)*xstride + k0 + kk);
        xl[(kk+0)*32 + r] = v.x;
        xl[(kk+1)*32 + r] = v.y;
        xl[(kk+2)*32 + r] = v.z;
        xl[(kk+3)*32 + r] = v.w;
      }
    }
    __syncthreads();
#pragma unroll 4
    for (int k = 0; k < 64; ++k){
      float4 w4 = *(const float4*)(wt + k*128 + tj*4);
      float4 x4 = *(const float4*)(xl + k*32  + tr*4);
      acc[0][0] = fmaf(x4.x, w4.x, acc[0][0]);
      acc[0][1] = fmaf(x4.x, w4.y, acc[0][1]);
      acc[0][2] = fmaf(x4.x, w4.z, acc[0][2]);
      acc[0][3] = fmaf(x4.x, w4.w, acc[0][3]);
      acc[1][0] = fmaf(x4.y, w4.x, acc[1][0]);
      acc[1][1] = fmaf(x4.y, w4.y, acc[1][1]);
      acc[1][2] = fmaf(x4.y, w4.z, acc[1][2]);
      acc[1][3] = fmaf(x4.y, w4.w, acc[1][3]);
      acc[2][0] = fmaf(x4.z, w4.x, acc[2][0]);
      acc[2][1] = fmaf(x4.z, w4.y, acc[2][1]);
      acc[2][2] = fmaf(x4.z, w4.z, acc[2][2]);
      acc[2][3] = fmaf(x4.z, w4.w, acc[2][3]);
      acc[3][0] = fmaf(x4.w, w4.x, acc[3][0]);
      acc[3][1] = fmaf(x4.w, w4.y, acc[3][1]);
      acc[3][2] = fmaf(x4.w, w4.z, acc[3][2]);
      acc[3][3] = fmaf(x4.w, w4.w, acc[3][3]);
    }
  }
  const size_t base = ((size_t)kb*R + r0 + tr*4)*nj + j0 + tj*4;
#pragma unroll
  for (int i = 0; i < 4; ++i)
    *(float4*)(part + base + (size_t)i*nj) = make_float4(acc[i][0], acc[i][1], acc[i][2], acc[i][3]);
}

__global__ __launch_bounds__(256) void mv2(
    const float* __restrict__ part, int R, int njshift, int KB,
    const float* __restrict__ b1, const float* __restrict__ b2,
    float* __restrict__ out, int rpgshift, int opg)
{
  int idx = blockIdx.x*256 + threadIdx.x;
  int nj = 1 << njshift;
  int r = idx >> njshift, j = idx & (nj - 1);
  float s = 0.f;
  if (b1) s += b1[j];
  if (b2) s += b2[j];
  size_t stride = (size_t)R << njshift;
  for (int kb = 0; kb < KB; ++kb) s += part[(size_t)kb*stride + idx];
  int orow = ((r >> rpgshift) * opg) + (r & ((1 << rpgshift) - 1));
  out[((size_t)orow << njshift) + j] = s;
}

// ---------------- genw: fused combine + D matvec; side-writes normalized ctx
// FULL=1: grid (8,16); FULL=0 (combine-only, t=Tn-1): grid (1,16).
template<int FULL>
__global__ __launch_bounds__(256) void genw(
    const float* __restrict__ ctxp, const float* __restrict__ mlp,
    const float* __restrict__ D, float* __restrict__ part, float* __restrict__ ctxout)
{
  __shared__ float wt[64*128];
  __shared__ float xl[64*32];
  const int t  = threadIdx.x;
  const int j0 = blockIdx.x * 128;
  const int kb = blockIdx.y;
  const int k0 = kb*64;
  const int tj = t & 31, tr = t >> 5;

  if (FULL){
    int j = t >> 1;
    int kqb = (t & 1) * 8;
    const float* Mrow = D + (size_t)(j0 + j)*1024 + k0;
#pragma unroll
    for (int c = 0; c < 8; ++c){
      float4 v = *(const float4*)(Mrow + (kqb + c)*4);
      int kk = (kqb + c)*4;
      wt[(kk+0)*128 + j] = v.x;
      wt[(kk+1)*128 + j] = v.y;
      wt[(kk+2)*128 + j] = v.z;
      wt[(kk+3)*128 + j] = v.w;
    }
  }
  {
    int b = t >> 3, kk = (t & 7)*8;
    float mx = -1e30f;
#pragma unroll
    for (int i = 0; i < 16; ++i) mx = fmaxf(mx, mlp[((size_t)b*16 + i)*2]);
    float L = 0.f;
    float a8[8] = {0.f,0.f,0.f,0.f,0.f,0.f,0.f,0.f};
#pragma unroll 4
    for (int i = 0; i < 16; ++i){
      float m = mlp[((size_t)b*16 + i)*2];
      float l = mlp[((size_t)b*16 + i)*2 + 1];
      float we = __expf(m - mx);
      L = fmaf(l, we, L);
      const float* cp = ctxp + ((size_t)b*16 + i)*1024 + k0 + kk;
      float4 u0 = *(const float4*)cp;
      float4 u1 = *(const float4*)(cp + 4);
      a8[0] = fmaf(we, u0.x, a8[0]); a8[1] = fmaf(we, u0.y, a8[1]);
      a8[2] = fmaf(we, u0.z, a8[2]); a8[3] = fmaf(we, u0.w, a8[3]);
      a8[4] = fmaf(we, u1.x, a8[4]); a8[5] = fmaf(we, u1.y, a8[5]);
      a8[6] = fmaf(we, u1.z, a8[6]); a8[7] = fmaf(we, u1.w, a8[7]);
    }
    float inv = 1.f / L;
#pragma unroll
    for (int q = 0; q < 8; ++q){
      float c = a8[q]*inv;
      if (FULL) xl[(kk + q)*32 + b] = c;
      if (!FULL || blockIdx.x == 0) ctxout[(size_t)b*1024 + k0 + kk + q] = c;
    }
  }
  if (!FULL) return;
  __syncthreads();
  float acc[4][4] = {{0.f,0.f,0.f,0.f},{0.f,0.f,0.f,0.f},{0.f,0.f,0.f,0.f},{0.f,0.f,0.f,0.f}};
#pragma unroll 4
  for (int k = 0; k < 64; ++k){
    float4 w4 = *(const float4*)(wt + k*128 + tj*4);
    float4 x4 = *(const float4*)(xl + k*32  + tr*4);
    acc[0][0] = fmaf(x4.x, w4.x, acc[0][0]);
    acc[0][1] = fmaf(x4.x, w4.y, acc[0][1]);
    acc[0][2] = fmaf(x4.x, w4.z, acc[0][2]);
    acc[0][3] = fmaf(x4.x, w4.w, acc[0][3]);
    acc[1][0] = fmaf(x4.y, w4.x, acc[1][0]);
    acc[1][1] = fmaf(x4.y, w4.y, acc[1][1]);
    acc[1][2] = fmaf(x4.y, w4.z, acc[1][2]);
    acc[1][3] = fmaf(x4.y, w4.w, acc[1][3]);
    acc[2][0] = fmaf(x4.z, w4.x, acc[2][0]);
    acc[2][1] = fmaf(x4.z, w4.y, acc[2][1]);
    acc[2][2] = fmaf(x4.z, w4.z, acc[2][2]);
    acc[2][3] = fmaf(x4.z, w4.w, acc[2][3]);
    acc[3][0] = fmaf(x4.w, w4.x, acc[3][0]);
    acc[3][1] = fmaf(x4.w, w4.y, acc[3][1]);
    acc[3][2] = fmaf(x4.w, w4.z, acc[3][2]);
    acc[3][3] = fmaf(x4.w, w4.w, acc[3][3]);
  }
  const size_t base = ((size_t)kb*32 + tr*4)*1024 + j0 + tj*4;
#pragma unroll
  for (int i = 0; i < 4; ++i)
    *(float4*)(part + base + (size_t)i*1024) = make_float4(acc[i][0], acc[i][1], acc[i][2], acc[i][3]);
}

// reduce batched Wv partials -> xs[b][t+1] (+bv). KB=16, R=224. grid 896, block 256.
__global__ __launch_bounds__(256) void mv2xs(
    const float* __restrict__ part, const float* __restrict__ bv, float* __restrict__ xs)
{
  int idx = blockIdx.x*256 + threadIdx.x;   // 224*1024
  int r = idx >> 10, j = idx & 1023;
  int t = r >> 5, b = r & 31;
  const size_t stride = (size_t)224*1024;
  float s = bv[j];
#pragma unroll
  for (int kb = 0; kb < 16; ++kb) s += part[(size_t)kb*stride + idx];
  xs[(((size_t)b*Tn) + t + 1)*1024 + j] = s;
}

// ---------------- stage-2 kernels ----------------

__global__ __launch_bounds__(512) void scores2_kernel(
    const float* __restrict__ hidden, const float* __restrict__ xk2, float* __restrict__ sc)
{
  int b = blockIdx.y, p = blockIdx.x;
  int lane = threadIdx.x & 63, w = threadIdx.x >> 6;
  int t0 = (w & 3) * 2, rh = w >> 2;
  const float4* qa = (const float4*)(xk2 + ((size_t)b*Tn + t0  )*Hn) + lane;
  const float4* qb = (const float4*)(xk2 + ((size_t)b*Tn + t0+1)*Hn) + lane;
  float4 a0=qa[0], a1=qa[64], a2=qa[128], a3=qa[192];
  float4 c0=qb[0], c1=qb[64], c2=qb[128], c3=qb[192];
#pragma unroll 2
  for (int r = 0; r < 8; ++r){
    int s = p*16 + rh*8 + r;
    const float4* row = (const float4*)(hidden + ((size_t)s*Bn + b)*Hn) + lane;
    float4 v0=row[0], v1=row[64], v2=row[128], v3=row[192];
    float d0 = wsum(dot16(a0,a1,a2,a3, v0,v1,v2,v3));
    float d1 = wsum(dot16(c0,c1,c2,c3, v0,v1,v2,v3));
    if (lane == 0){
      sc[((size_t)b*Tn + t0  )*Sn + s] = d0;
      sc[((size_t)b*Tn + t0+1)*Sn + s] = d1;
    }
  }
}

__global__ __launch_bounds__(512) void softmax512(float* __restrict__ sc){
  int row = blockIdx.x, tid = threadIdx.x, lane = tid & 63, w = tid >> 6;
  float v = sc[(size_t)row*Sn + tid];
  float mx = v;
#pragma unroll
  for (int off = 32; off; off >>= 1) mx = fmaxf(mx, __shfl_xor(mx, off));
  __shared__ float sm[8], ss[8];
  if (lane == 0) sm[w] = mx;
  __syncthreads();
  mx = sm[0];
#pragma unroll
  for (int i = 1; i < 8; ++i) mx = fmaxf(mx, sm[i]);
  float e = __expf(v - mx);
  float s = e;
#pragma unroll
  for (int off = 32; off; off >>= 1) s += __shfl_xor(s, off);
  if (lane == 0) ss[w] = s;
  __syncthreads();
  float tot = 0.f;
#pragma unroll
  for (int i = 0; i < 8; ++i) tot += ss[i];
  sc[(size_t)row*Sn + tid] = e / tot;
}

__global__ __launch_bounds__(512) void ctx2p(
    const float* __restrict__ hidden, const float* __restrict__ attn, float* __restrict__ part)
{
  int hc = blockIdx.x, sc = blockIdx.y, b = blockIdx.z;
  int tid = threadIdx.x, hloc = tid & 127, tg = tid >> 7;
  __shared__ float al[Tn*128];
  for (int idx = tid; idx < Tn*128; idx += 512){
    int t = idx >> 7, si = idx & 127;
    al[idx] = attn[((size_t)b*Tn + t)*Sn + sc*128 + si];
  }
  __syncthreads();
  int h = hc*128 + hloc, t0 = tg*2;
  float acc0 = 0.f, acc1 = 0.f;
#pragma unroll 4
  for (int si = 0; si < 128; ++si){
    int s = sc*128 + si;
    float v = hidden[((size_t)s*Bn + b)*Hn + h];
    acc0 = fmaf(al[t0*128 + si],     v, acc0);
    acc1 = fmaf(al[(t0+1)*128 + si], v, acc1);
  }
  part[(((size_t)sc*Bn + b)*Tn + t0  )*Hn + h] = acc0;
  part[(((size_t)sc*Bn + b)*Tn + t0+1)*Hn + h] = acc1;
}

__global__ __launch_bounds__(256) void ctx2r(const float* __restrict__ part, float* __restrict__ out){
  int idx = blockIdx.x*256 + threadIdx.x;   // 262144
  out[idx] = part[idx] + part[262144 + idx] + part[524288 + idx] + part[786432 + idx];
}

// ---------------- LSTM: fused partial-reduce + pointwise ----------------
__global__ __launch_bounds__(256) void lstm_fused(
    const float* __restrict__ part, const float* __restrict__ b_ih,
    const float* __restrict__ b_hh, float* __restrict__ fq)
{
  int idx = blockIdx.x*256 + threadIdx.x;   // 32768
  int b = idx >> 10, h = idx & 1023;
  const size_t stride = (size_t)32*Gn;
  float gi = b_ih[h] + b_hh[h];
  float gg = b_ih[2048+h] + b_hh[2048+h];
  float go = b_ih[3072+h] + b_hh[3072+h];
  for (int kb = 0; kb < 16; ++kb){
    const float* pp = part + (size_t)kb*stride + (size_t)b*Gn;
    gi += pp[h]; gg += pp[2048+h]; go += pp[3072+h];
  }
  float si = 1.f/(1.f + __expf(-gi));
  float so = 1.f/(1.f + __expf(-go));
  float c  = si * tanhf(gg);
  fq[((size_t)b*(Tn+1) + Tn)*Hn + h] = so * tanhf(c);
}

// ---------------- host ----------------

extern "C" void kernel_launch(void* const* d_in, const int* in_sizes, int n_in,
                              void* d_out, int out_size, void* d_ws, size_t ws_size,
                              hipStream_t stream) {
  const float* hidden = (const float*)d_in[0];
  const float* nums   = (const float*)d_in[1];
  const float* pq     = (const float*)d_in[2];
  const float* Wk     = (const float*)d_in[3];
  const float* Wv     = (const float*)d_in[5];
  const float* bv     = (const float*)d_in[6];
  const float* Wk2    = (const float*)d_in[7];
  const float* Wv2    = (const float*)d_in[9];
  const float* bv2    = (const float*)d_in[10];
  const float* W_ih   = (const float*)d_in[11];
  const float* b_ih   = (const float*)d_in[13];
  const float* b_hh   = (const float*)d_in[14];

  float* out = (float*)d_out;
  float* fq  = out;                                   // (B, T+1, H)
  float* uh  = out + (size_t)Bn*(Tn+1)*Hn;            // (S+T, B, H)
  float* un  = uh + (size_t)(Sn+Tn)*Bn*Hn;            // (B, N+T, H)

  // ws layout (floats); high-water 11,668,480 floats = 46.7 MB
  // (ws_size proven >= 56 MB: R3's bf16 path, guarded at 56 MB, was active)
  float* ws    = (float*)d_ws;
  float* xs    = ws;                 // 262144
  float* ctxp  = ws + 262144;        // 524288 (B*16*H)
  float* mlp   = ws + 1310720;       // 512
  float* xk2   = ws + 1345536;       // 262144
  float* sc2   = ws + 1607680;       // 131072
  float* ctx2v = ws + 1738752;       // 262144
  float* partX = ws + 2000896;       // 524288 (16*32*1024)
  float* partK = ws + 2525184;       // 524288
  float* WkT   = ws + 3049472;       // 1048576
  float* Wk2T  = ws + 4098048;       // 1048576
  float* WvT   = ws + 5146624;       // 1048576
  float* Dcomb = ws + 6195200;       // 1048576 (D[j][i] = sum_m Wk[m][j] Wv[m][i])
  float* ctxall= ws + 7243776;       // 229376 (7*32*1024 normalized ctx per step)
  float* dk    = ws + 7473152;       // 1024  (dk[j] = sum_m bv[m] Wk[m][j])
  float* Dparts= ws + 7474176;       // 4194304 (split-K partials: Dcomb KB=4, then 256-row mv KB=16)
  float* c2part= partX;              // ctx2 split-s partials (spans partX+partK, disjoint lifetime)
  float* partL = WkT;                // LSTM partials 16*32*4096 (WkT/Wk2T dead by then)

  transpose3<<<dim3(32,32,3), 256, 0, stream>>>(Wk, Wk2, Wv, WkT, Wk2T, WvT);
  prep<<<dim3(Nn+1, Bn), 256, 0, stream>>>((const float4*)nums, (const float4*)pq, (float4*)un, (float4*)xs);
  // one-time: D = Wk^T * Wv -- split-K KB=4 (1024 blocks, 4/CU) + reduce
  mv1<<<dim3(8,4,32), 256, 0, stream>>>(WkT, Hn, WvT, Dparts, Hn, 4);
  mv2<<<4096, 256, 0, stream>>>(Dparts, 1024, 10, 4, nullptr, nullptr, Dcomb, 0, 1);
  dkv<<<256, 256, 0, stream>>>(bv, WkT, dk);

  // xk0 partials = Wk^T problem_q (attend folds the reduce itself)
  mv1<<<dim3(8,16,1), 256, 0, stream>>>(pq, Hn, WkT, partK, Hn, 1);

  for (int t = 1; t < Tn; ++t){
    if (t == 1) attend10<1><<<dim3(16,Bn), 512, 0, stream>>>(hidden, partK, nullptr, ctxp, mlp, uh);
    else        attend10<0><<<dim3(16,Bn), 512, 0, stream>>>(hidden, partX, dk, ctxp, mlp, uh);
    float* ctxt = ctxall + (size_t)(t-1)*Bn*Hn;
    if (t < Tn-1) genw<1><<<dim3(8,16), 256, 0, stream>>>(ctxp, mlp, Dcomb, partX, ctxt);
    else          genw<0><<<dim3(1,16), 256, 0, stream>>>(ctxp, mlp, Dcomb, partX, ctxt);
  }

  // xs[:,1..7,:] = ctxall @ Wv^T + bv  (batched; KB=16 -> 896 blocks)
  mv1<<<dim3(8,16,7), 256, 0, stream>>>(ctxall, Hn, Wv, Dparts, Hn, 1);
  mv2xs<<<896, 256, 0, stream>>>(Dparts, bv, xs);

  // stage 2 (256-row matvecs at KB=16 -> 1024 blocks each)
  mv1<<<dim3(8,16,8), 256, 0, stream>>>(xs, Hn, Wk2T, Dparts, Hn, 1);
  mv2<<<1024, 256, 0, stream>>>(Dparts, 256, 10, 16, nullptr, nullptr, xk2, 0, 1);
  scores2_kernel<<<dim3(32, Bn), 512, 0, stream>>>(hidden, xk2, sc2);
  softmax512<<<Bn*Tn, 512, 0, stream>>>(sc2);
  ctx2p<<<dim3(8, 4, Bn), 512, 0, stream>>>(hidden, sc2, c2part);
  ctx2r<<<1024, 256, 0, stream>>>(c2part, ctx2v);
  mv1<<<dim3(8,16,8), 256, 0, stream>>>(ctx2v, Hn, Wv2, Dparts, Hn, 1);
  mv2<<<1024, 256, 0, stream>>>(Dparts, 256, 10, 16, bv2, nullptr, fq, 3, Tn+1);

  // LSTM step 1 (partials overlay WkT/Wk2T -- dead by now)
  mv1<<<dim3(32,16,1), 256, 0, stream>>>(fq, (Tn+1)*Hn, W_ih, partL, Gn, 1);
  lstm_fused<<<128, 256, 0, stream>>>(partL, b_ih, b_hh, fq);

  finalize_xs<<<dim3(Tn, Bn), 256, 0, stream>>>((const float4*)xs, (float4*)uh, (float4*)un);
}